// Round 6
// baseline (2676.821 us; speedup 1.0000x reference)
//
#include <hip/hip_runtime.h>
#include <hip/hip_bf16.h>
#include <cmath>

#define TT 1024
#define DD 1024
#define HH 16
#define LL 4
#define BB 2
#define DHH 64
#define DFF 4096
#define VV 50257

typedef float floatx4 __attribute__((ext_vector_type(4)));
typedef __bf16 bf16x8 __attribute__((ext_vector_type(8)));

typedef unsigned int u32;
typedef __attribute__((address_space(1))) const u32 gu32;
typedef __attribute__((address_space(3))) u32 lu32;

__device__ __forceinline__ void gload16(const unsigned short* g, unsigned short* l) {
  __builtin_amdgcn_global_load_lds((gu32*)g, (lu32*)l, 16, 0, 0);
}

__device__ __forceinline__ unsigned short f2bf(float f) {
  unsigned u = __float_as_uint(f);
  u += 0x7fffu + ((u >> 16) & 1u);
  return (unsigned short)(u >> 16);
}
__device__ __forceinline__ float bf2f(unsigned short u) {
  return __uint_as_float(((unsigned)u) << 16);
}

__device__ __forceinline__ float wave_sum(float v) {
#pragma unroll
  for (int off = 1; off < 64; off <<= 1) v += __shfl_xor(v, off);
  return v;
}
__device__ __forceinline__ float wave_max(float v) {
#pragma unroll
  for (int off = 1; off < 64; off <<= 1) v = fmaxf(v, __shfl_xor(v, off));
  return v;
}

// ---------------- GEMM: C = A[M,K] * B[N,K]^T, bf16 inputs, fp32 acc ----------------
#define EPI_F32 0   // fp32 store (also split-K partials via kchunk)
#define EPI_QKV 1
#define EPI_ATT 2
#define EPI_GELU 3
#define EPI_LSE 4
#define EPI_SBF 5   // bf16 raw-S store, lower-triangular block grid

struct GemmArgs {
  const unsigned short* A;   // [M,K] bf16 (batched via aBatch)
  const unsigned short* B;   // [N,K] bf16 (batched via bBatch)
  long aBatch, bBatch, cBatch;
  int M, N, K, ldc;
  float* outF;               // EPI_F32 / EPI_LSE
  unsigned short* q;         // EPI_QKV
  unsigned short* kk;
  unsigned short* vt;
  unsigned short* outB;      // EPI_ATT / EPI_GELU / EPI_SBF
  const float* bias;         // EPI_GELU
  float2* lsePart;           // EPI_LSE per-(row,block) partials
  int pn;                    // EPI_LSE: N-block count
  int kchunk;                // split-K: K per z-split (0 = no split, z = batch)
  int mfirst;                // 1: blockIdx.x = M-block (L2 B-panel sharing)
};

template <int EPI>
__global__ __launch_bounds__(256) void gemm_kernel(GemmArgs ga) {
  __shared__ __align__(16) unsigned short As[128 * 32];
  __shared__ __align__(16) unsigned short Bs[128 * 32];
  const int tid = threadIdx.x;
  int bm, bn;
  if constexpr (EPI == EPI_SBF) {
    // packed lower-triangular block index -> (r,c), r >= c
    const int xb = blockIdx.x;
    int r = (int)((sqrtf(8.f * xb + 1.f) - 1.f) * 0.5f);
    if ((r * (r + 1)) / 2 > xb) --r;
    else if (((r + 1) * (r + 2)) / 2 <= xb) ++r;
    const int c = xb - (r * (r + 1)) / 2;
    bm = r * 128; bn = c * 128;
  } else if (ga.mfirst) {
    bm = blockIdx.x * 128; bn = blockIdx.y * 128;
  } else {
    bm = blockIdx.y * 128; bn = blockIdx.x * 128;
  }
  const int z = blockIdx.z;
  const unsigned short* A = ga.A + (long)z * ga.aBatch;
  const unsigned short* Bp = ga.B + (long)z * ga.bBatch;
  const int K = ga.K, N = ga.N;

  int kbeg = 0, kend = K;
  if (ga.kchunk) { kbeg = z * ga.kchunk; kend = kbeg + ga.kchunk; }
  if constexpr (EPI == EPI_ATT) {
    // causal: w[m,k] == 0 for k > m (softmax wrote exact zeros) -> clamp K
    kend = bm + 128;
  }

  floatx4 acc[4][4];
#pragma unroll
  for (int i = 0; i < 4; ++i)
#pragma unroll
    for (int j = 0; j < 4; ++j) acc[i][j] = (floatx4){0.f, 0.f, 0.f, 0.f};

  const int lane = tid & 63, wave = tid >> 6;
  const int wm = (wave & 1) * 64, wn = (wave >> 1) * 64;
  const int fr = lane & 15, quad = lane >> 4;
  const int srow = tid >> 2;           // 0..63
  const int sc8 = (tid & 3) * 8;       // 0,8,16,24 shorts

  // LDS dest is wave-uniform base + lane*16B; layout is exactly lane-linear:
  // byte off = (srow*32 + sc8)*2 = tid*16 within each 64-row half-tile.
  unsigned short* lA0 = &As[wave * 512];
  unsigned short* lA1 = &As[2048 + wave * 512];
  unsigned short* lB0 = &Bs[wave * 512];
  unsigned short* lB1 = &Bs[2048 + wave * 512];

  for (int k0 = kbeg; k0 < kend; k0 += 32) {
    const long ra = (long)(bm + srow) * K + (k0 + sc8);
    const long rb = (long)(bn + srow) * K + (k0 + sc8);
    gload16(A + ra, lA0);
    gload16(A + ra + 64L * K, lA1);
    gload16(Bp + rb, lB0);
    gload16(Bp + rb + 64L * K, lB1);
    __syncthreads();   // compiler drains vmcnt before barrier
    bf16x8 af[4], bfr[4];
#pragma unroll
    for (int i = 0; i < 4; ++i) af[i] = *(const bf16x8*)(&As[(wm + i * 16 + fr) * 32 + quad * 8]);
#pragma unroll
    for (int j = 0; j < 4; ++j) bfr[j] = *(const bf16x8*)(&Bs[(wn + j * 16 + fr) * 32 + quad * 8]);
#pragma unroll
    for (int i = 0; i < 4; ++i)
#pragma unroll
      for (int j = 0; j < 4; ++j)
        acc[i][j] = __builtin_amdgcn_mfma_f32_16x16x32_bf16(af[i], bfr[j], acc[i][j], 0, 0, 0);
    __syncthreads();
  }

  if constexpr (EPI == EPI_LSE) {
    // store logits + per-row (max, sumexp) partial. Two-pass (pure-fmax
    // reduce, then independent exps + pure-add reduce): no dependent
    // exp chains, ~2x fewer transcendentals than online merging.
    const int nblk = ga.mfirst ? blockIdx.y : blockIdx.x;
    float2* sm = (float2*)As;   // As is free after K-loop barrier
#pragma unroll
    for (int i = 0; i < 4; ++i) {
#pragma unroll
      for (int r = 0; r < 4; ++r) {
        const int m = bm + wm + i * 16 + quad * 4 + r;
        float mx = -INFINITY;
#pragma unroll
        for (int j = 0; j < 4; ++j) {
          const int n = bn + wn + j * 16 + fr;
          if (n < N) {
            const float val = acc[i][j][r];
            __builtin_nontemporal_store(val, &ga.outF[(long)m * ga.ldc + n]);
            mx = fmaxf(mx, val);
          }
        }
#pragma unroll
        for (int off = 1; off < 16; off <<= 1) mx = fmaxf(mx, __shfl_xor(mx, off));
        float ss = 0.f;
#pragma unroll
        for (int j = 0; j < 4; ++j) {
          const int n = bn + wn + j * 16 + fr;
          if (n < N) ss += __expf(acc[i][j][r] - mx);
        }
#pragma unroll
        for (int off = 1; off < 16; off <<= 1) ss += __shfl_xor(ss, off);
        if (fr == 0) {
          const int rl = wm + i * 16 + quad * 4 + r;
          sm[rl * 2 + (wave >> 1)] = make_float2(mx, ss);
        }
      }
    }
    __syncthreads();
    if (tid < 128) {
      const float2 a = sm[tid * 2], b = sm[tid * 2 + 1];
      const float M = fmaxf(a.x, b.x);
      const float S = a.y * __expf(a.x - M) + b.y * __expf(b.x - M);
      ga.lsePart[(long)(bm + tid) * ga.pn + nblk] = make_float2(M, S);
    }
  } else {
#pragma unroll
    for (int i = 0; i < 4; ++i) {
#pragma unroll
      for (int j = 0; j < 4; ++j) {
        const int n = bn + wn + j * 16 + fr;
#pragma unroll
        for (int r = 0; r < 4; ++r) {
          const int m = bm + wm + i * 16 + quad * 4 + r;
          const float val = acc[i][j][r];
          if constexpr (EPI == EPI_F32) {
            if (n < N) ga.outF[(long)z * ga.cBatch + (long)m * ga.ldc + n] = val;
          }
          if constexpr (EPI == EPI_SBF) {
            ga.outB[(long)z * TT * TT + (long)m * TT + n] = f2bf(val);
          }
          if constexpr (EPI == EPI_QKV) {
            const int b = m >> 10, t = m & 1023;
            const int sec = n >> 10, col = n & 1023;
            const int hd = col >> 6, dh = col & 63;
            const unsigned short bv = f2bf(val);
            if (sec == 0)      ga.q [((long)(b * HH + hd) * TT + t) * DHH + dh] = bv;
            else if (sec == 1) ga.kk[((long)(b * HH + hd) * TT + t) * DHH + dh] = bv;
            else               ga.vt[((long)(b * HH + hd) * DHH + dh) * TT + t] = bv;
          }
          if constexpr (EPI == EPI_ATT) {
            if (n < 64) {
              const int b = z >> 4, hd = z & 15;
              ga.outB[((long)(b * TT + m)) * DD + hd * DHH + n] = f2bf(val);
            }
          }
          if constexpr (EPI == EPI_GELU) {
            const float xx = val + ga.bias[n];
            const float gl = 0.5f * xx * (1.f + erff(xx * 0.7071067811865475f));
            ga.outB[(long)m * DFF + n] = f2bf(gl);
          }
        }
      }
    }
  }
}

// -------- transpose fp32 [R,C] -> bf16 [C,R], layer-batched via blockIdx.z --------
__global__ __launch_bounds__(256) void transpose_bf16_kernel(const float* __restrict__ src0,
    unsigned short* __restrict__ dst0, int R, int C, long sStride, long dStride) {
  const float* src = src0 + (long)blockIdx.z * sStride;
  unsigned short* dst = dst0 + (long)blockIdx.z * dStride;
  __shared__ float tile[32][33];
  const int c0 = blockIdx.x * 32, r0 = blockIdx.y * 32;
  const int tx = threadIdx.x & 31, ty = threadIdx.x >> 5;
#pragma unroll
  for (int rr = ty; rr < 32; rr += 8)
    tile[rr][tx] = src[(long)(r0 + rr) * C + (c0 + tx)];
  __syncthreads();
#pragma unroll
  for (int rr = ty; rr < 32; rr += 8)
    dst[(long)(c0 + rr) * R + (r0 + tx)] = f2bf(tile[tx][rr]);
}

__global__ __launch_bounds__(256) void convert_bf16_kernel(const float* __restrict__ in,
    unsigned short* __restrict__ out) {
  const long i = (long)blockIdx.x * 256 + threadIdx.x;
  const float4 v = ((const float4*)in)[i];
  ushort4 o;
  o.x = f2bf(v.x); o.y = f2bf(v.y); o.z = f2bf(v.z); o.w = f2bf(v.w);
  ((ushort4*)out)[i] = o;
}

__global__ __launch_bounds__(256) void embed_kernel(const int* __restrict__ idx,
    const float* __restrict__ emb, const float* __restrict__ pos, float* __restrict__ x) {
  const int bt = blockIdx.x;
  const int t = bt & (TT - 1);
  const int tok = idx[bt];
  const float4 e = ((const float4*)(emb + (long)tok * DD))[threadIdx.x];
  const float4 p = ((const float4*)(pos + (long)t * DD))[threadIdx.x];
  float4 o; o.x = e.x + p.x; o.y = e.y + p.y; o.z = e.z + p.z; o.w = e.w + p.w;
  ((float4*)(x + (long)bt * DD))[threadIdx.x] = o;
}

// LN; optionally fuses the residual partial-sum (x += p0 + p1 + bias) first.
__global__ __launch_bounds__(256) void ln_kernel(const float* __restrict__ x,
    const float* __restrict__ g, const float* __restrict__ b, unsigned short* __restrict__ out) {
  const int row = blockIdx.x;
  const float4 v = ((const float4*)(x + (long)row * DD))[threadIdx.x];
  float s = v.x + v.y + v.z + v.w;
  float s2 = v.x * v.x + v.y * v.y + v.z * v.z + v.w * v.w;
  s = wave_sum(s); s2 = wave_sum(s2);
  __shared__ float ps[4], ps2[4];
  const int wv = threadIdx.x >> 6, lane = threadIdx.x & 63;
  if (lane == 0) { ps[wv] = s; ps2[wv] = s2; }
  __syncthreads();
  s = ps[0] + ps[1] + ps[2] + ps[3];
  s2 = ps2[0] + ps2[1] + ps2[2] + ps2[3];
  const float mean = s * (1.f / DD);
  const float var = s2 * (1.f / DD) - mean * mean;
  const float rs = rsqrtf(var + 1e-5f);
  const float4 gv = ((const float4*)g)[threadIdx.x];
  const float4 bv = ((const float4*)b)[threadIdx.x];
  ushort4 o;
  o.x = f2bf((v.x - mean) * rs * gv.x + bv.x);
  o.y = f2bf((v.y - mean) * rs * gv.y + bv.y);
  o.z = f2bf((v.z - mean) * rs * gv.z + bv.z);
  o.w = f2bf((v.w - mean) * rs * gv.w + bv.w);
  ((ushort4*)(out + (long)row * DD))[threadIdx.x] = o;
}

__global__ __launch_bounds__(256) void ln_fuse_kernel(float* __restrict__ x,
    const float* __restrict__ p0, const float* __restrict__ p1,
    const float* __restrict__ bias,
    const float* __restrict__ g, const float* __restrict__ b,
    unsigned short* __restrict__ out) {
  const int row = blockIdx.x;
  float4 v = ((const float4*)(x + (long)row * DD))[threadIdx.x];
  const float4 a0 = ((const float4*)(p0 + (long)row * DD))[threadIdx.x];
  const float4 a1 = ((const float4*)(p1 + (long)row * DD))[threadIdx.x];
  v.x += a0.x + a1.x; v.y += a0.y + a1.y; v.z += a0.z + a1.z; v.w += a0.w + a1.w;
  if (bias) {
    const float4 bb = ((const float4*)bias)[threadIdx.x];
    v.x += bb.x; v.y += bb.y; v.z += bb.z; v.w += bb.w;
  }
  ((float4*)(x + (long)row * DD))[threadIdx.x] = v;
  float s = v.x + v.y + v.z + v.w;
  float s2 = v.x * v.x + v.y * v.y + v.z * v.z + v.w * v.w;
  s = wave_sum(s); s2 = wave_sum(s2);
  __shared__ float ps[4], ps2[4];
  const int wv = threadIdx.x >> 6, lane = threadIdx.x & 63;
  if (lane == 0) { ps[wv] = s; ps2[wv] = s2; }
  __syncthreads();
  s = ps[0] + ps[1] + ps[2] + ps[3];
  s2 = ps2[0] + ps2[1] + ps2[2] + ps2[3];
  const float mean = s * (1.f / DD);
  const float var = s2 * (1.f / DD) - mean * mean;
  const float rs = rsqrtf(var + 1e-5f);
  const float4 gv = ((const float4*)g)[threadIdx.x];
  const float4 bv = ((const float4*)b)[threadIdx.x];
  ushort4 o;
  o.x = f2bf((v.x - mean) * rs * gv.x + bv.x);
  o.y = f2bf((v.y - mean) * rs * gv.y + bv.y);
  o.z = f2bf((v.z - mean) * rs * gv.z + bv.z);
  o.w = f2bf((v.w - mean) * rs * gv.w + bv.w);
  ((ushort4*)(out + (long)row * DD))[threadIdx.x] = o;
}

// all layers batched via blockIdx.z
__global__ __launch_bounds__(256) void dists_kernel(const float* __restrict__ pos0,
    float* __restrict__ dout0, float* __restrict__ tre_acc) {
  const float* pos = pos0 + (long)blockIdx.z * TT * 3;
  float* dout = dout0 + (long)blockIdx.z * TT * TT;
  const int i = blockIdx.x;
  const float px = pos[i * 3], py = pos[i * 3 + 1], pz = pos[i * 3 + 2];
  float rsum = 0.f;
#pragma unroll
  for (int c = 0; c < 4; ++c) {
    const int j = c * 256 + threadIdx.x;
    const float dx = px - pos[j * 3];
    const float dy = py - pos[j * 3 + 1];
    const float dz = pz - pos[j * 3 + 2];
    const float sq = dx * dx + dy * dy + dz * dz;
    const float d = sq > 0.f ? sqrtf(sq) : 0.f;
    dout[(long)i * TT + j] = d;
    if (j != i) rsum += 1.f / (d + 1e-4f);
  }
  rsum = wave_sum(rsum);
  __shared__ float ps[4];
  const int wv = threadIdx.x >> 6, lane = threadIdx.x & 63;
  if (lane == 0) ps[wv] = rsum;
  __syncthreads();
  if (threadIdx.x == 0) atomicAdd(tre_acc, ps[0] + ps[1] + ps[2] + ps[3]);
}

// Reads raw bf16 S from wb (lower-triangular blocks valid; rest masked here),
// writes w fp32 to W (the all_w output) and bf16 w back into wb in-place.
__global__ __launch_bounds__(256) void softmax_kernel(unsigned short* __restrict__ wb,
    const float* __restrict__ dists, float* __restrict__ W,
    float2* __restrict__ partials) {
  const long row = blockIdx.x;  // z*T + i
  const int i = (int)(row & (TT - 1));
  unsigned short* sr = wb + row * TT;
  const float* dr = dists + (long)i * TT;
  const int j0 = threadIdx.x * 4;

  const float4 dv = ((const float4*)dr)[threadIdx.x];
  const ushort4 su = ((const ushort4*)sr)[threadIdx.x];
  float d[4] = {dv.x, dv.y, dv.z, dv.w};
  float sa[4] = {bf2f(su.x), bf2f(su.y), bf2f(su.z), bf2f(su.w)};
  float l[4];
  float mx = -INFINITY;
#pragma unroll
  for (int c = 0; c < 4; ++c) {
    float v = sa[c] * 0.125f - d[c];   // scale = 1/sqrt(64), PEN = 1.0
    if (j0 + c > i) v = -INFINITY;
    l[c] = v;
    mx = fmaxf(mx, v);
  }
  mx = wave_max(mx);
  __shared__ float rmax[4], rsm[4], rwd[4], rent[4];
  const int wv = threadIdx.x >> 6, lane = threadIdx.x & 63;
  if (lane == 0) rmax[wv] = mx;
  __syncthreads();
  mx = fmaxf(fmaxf(rmax[0], rmax[1]), fmaxf(rmax[2], rmax[3]));
  float e[4], sum = 0.f;
#pragma unroll
  for (int c = 0; c < 4; ++c) { e[c] = __expf(l[c] - mx); sum += e[c]; }
  sum = wave_sum(sum);
  if (lane == 0) rsm[wv] = sum;
  __syncthreads();
  sum = rsm[0] + rsm[1] + rsm[2] + rsm[3];
  const float inv = 1.f / sum;
  floatx4 wo;
  ushort4 bo;
  const float w0 = e[0] * inv, w1 = e[1] * inv, w2 = e[2] * inv, w3 = e[3] * inv;
  wo[0] = w0; wo[1] = w1; wo[2] = w2; wo[3] = w3;
  bo.x = f2bf(w0); bo.y = f2bf(w1); bo.z = f2bf(w2); bo.w = f2bf(w3);
  float wd = w0 * d[0] + w1 * d[1] + w2 * d[2] + w3 * d[3];
  float ent = -(w0 * __logf(w0 + 1e-9f) + w1 * __logf(w1 + 1e-9f)
        + w2 * __logf(w2 + 1e-9f) + w3 * __logf(w3 + 1e-9f));
  __builtin_nontemporal_store(wo, (floatx4*)(W + row * TT) + threadIdx.x);
  ((ushort4*)sr)[threadIdx.x] = bo;
  wd = wave_sum(wd); ent = wave_sum(ent);
  if (lane == 0) { rwd[wv] = wd; rent[wv] = ent; }
  __syncthreads();
  if (threadIdx.x == 0) {
    partials[row] = make_float2(rwd[0] + rwd[1] + rwd[2] + rwd[3],
                                rent[0] + rent[1] + rent[2] + rent[3]);
  }
}

// grid-stride reduce of float2 partials into two accumulators (few atomics total)
__global__ __launch_bounds__(256) void reduce_partials_kernel(const float2* __restrict__ p,
    int n, float* __restrict__ tde_acc, float* __restrict__ tfe_acc) {
  float wd = 0.f, ent = 0.f;
  for (int i = blockIdx.x * 256 + threadIdx.x; i < n; i += gridDim.x * 256) {
    const float2 v = p[i];
    wd += v.x; ent += v.y;
  }
  wd = wave_sum(wd); ent = wave_sum(ent);
  __shared__ float pw[4], pe[4];
  const int wv = threadIdx.x >> 6, lane = threadIdx.x & 63;
  if (lane == 0) { pw[wv] = wd; pe[wv] = ent; }
  __syncthreads();
  if (threadIdx.x == 0) {
    atomicAdd(tde_acc, pw[0] + pw[1] + pw[2] + pw[3]);
    atomicAdd(tfe_acc, pe[0] + pe[1] + pe[2] + pe[3]);
  }
}

// combine per-block LSE partials -> CE (replaces full 412MB logits re-read)
__global__ __launch_bounds__(256) void ce_reduce_kernel(const float2* __restrict__ part,
    const float* __restrict__ logits, const int* __restrict__ targets,
    float* __restrict__ ce_acc, int pn) {
  const int row = blockIdx.x;
  const float2* pr = part + (long)row * pn;
  float m = -INFINITY, s = 0.f;
  for (int i = threadIdx.x; i < pn; i += 256) {
    const float2 v = pr[i];
    const float M = fmaxf(m, v.x);
    s = s * __expf(m - M) + v.y * __expf(v.x - M);
    m = M;
  }
#pragma unroll
  for (int off = 1; off < 64; off <<= 1) {
    const float mo = __shfl_xor(m, off), so = __shfl_xor(s, off);
    const float M = fmaxf(m, mo);
    s = s * __expf(m - M) + so * __expf(mo - M);
    m = M;
  }
  __shared__ float pm[4], psv[4];
  const int wv = threadIdx.x >> 6, lane = threadIdx.x & 63;
  if (lane == 0) { pm[wv] = m; psv[wv] = s; }
  __syncthreads();
  if (threadIdx.x == 0) {
    const float M = fmaxf(fmaxf(pm[0], pm[1]), fmaxf(pm[2], pm[3]));
    const float S = psv[0] * __expf(pm[0] - M) + psv[1] * __expf(pm[1] - M)
                  + psv[2] * __expf(pm[2] - M) + psv[3] * __expf(pm[3] - M);
    atomicAdd(ce_acc, M + logf(S) - logits[(long)row * VV + targets[row]]);
  }
}

__global__ void zero_acc_kernel(float* p) { if (threadIdx.x < 4) p[threadIdx.x] = 0.f; }

__global__ void finalize_kernel(const float* __restrict__ acc, float* __restrict__ o) {
  if (threadIdx.x == 0) {
    const float tde = acc[0] * (1.f / 32768.f);   // /(B*H*T)
    const float tfe = acc[1] * (1.f / 32768.f);
    const float tre = acc[2] * (1.f / 1047552.f); // /(T*T-T)
    const float ce = acc[3] * (1.f / 2048.f);     // /(B*T)
    o[0] = ce + 0.01f * tde + 0.1f * tfe + 0.01f * tre;
    o[1] = tde; o[2] = tfe; o[3] = tre;
  }
}

extern "C" void kernel_launch(void* const* d_in, const int* in_sizes, int n_in,
                              void* d_out, int out_size, void* d_ws, size_t ws_size,
                              hipStream_t stream) {
  const int* idx = (const int*)d_in[0];
  const int* targets = (const int*)d_in[1];
  const float* emb = (const float*)d_in[2];
  const float* pos_emb = (const float*)d_in[3];
  const float* positions = (const float*)d_in[4];
  const float* ln1_g = (const float*)d_in[5];
  const float* ln1_b = (const float*)d_in[6];
  const float* ln2_g = (const float*)d_in[7];
  const float* ln2_b = (const float*)d_in[8];
  const float* lnf_g = (const float*)d_in[9];
  const float* lnf_b = (const float*)d_in[10];
  const float* qkv_w = (const float*)d_in[11];
  const float* proj_w = (const float*)d_in[12];
  const float* w1 = (const float*)d_in[13];
  const float* b1 = (const float*)d_in[14];
  const float* w2 = (const float*)d_in[15];
  const float* b2 = (const float*)d_in[16];

  float* out = (float*)d_out;
  char* ws = (char*)d_ws;

  // output offsets (floats)
  const long LOGITS_N = (long)BB * TT * VV;              // 102,926,336
  const long SCAL_OFF = LOGITS_N;                        // loss, tde, tfe, tre
  const long ALLW_OFF = LOGITS_N + 4;
  const long ALLW_STRIDE = (long)BB * HH * TT * TT;      // 33,554,432
  const long ALLD_OFF = ALLW_OFF + 4 * ALLW_STRIDE;
  const long ALLD_STRIDE = (long)TT * TT;

  // workspace layout (bytes)
  unsigned short* wt_qkv  = (unsigned short*)(ws);                 // 25,165,824
  unsigned short* wt_proj = (unsigned short*)(ws + 25165824L);     //  8,388,608
  unsigned short* wt_w1   = (unsigned short*)(ws + 33554432L);     // 33,554,432
  unsigned short* wt_w2   = (unsigned short*)(ws + 67108864L);     // 33,554,432
  unsigned short* emb_bf  = (unsigned short*)(ws + 100663296L);    // 102,926,336
  float*          x       = (float*)(ws + 203589632L);             //  8,388,608
  unsigned short* h_bf    = (unsigned short*)(ws + 211978240L);    //  4,194,304
  unsigned short* q_bf    = (unsigned short*)(ws + 216172544L);    //  4,194,304
  unsigned short* k_bf    = (unsigned short*)(ws + 220366848L);    //  4,194,304
  unsigned short* vt_bf   = (unsigned short*)(ws + 224561152L);    //  4,194,304
  unsigned short* attb_bf = (unsigned short*)(ws + 228755456L);    //  4,194,304
  unsigned short* g_bf    = (unsigned short*)(ws + 232949760L);    // 16,777,216
  unsigned short* w_bf    = (unsigned short*)(ws + 249726976L);    // 67,108,864
  float*          accs    = (float*)(ws + 316835840L);             //        16

  // scratch overlays (lifetime-checked):
  //  - smpart: softmax per-row partials in attb_bf (dead until AV writes it;
  //    consumed by reduce_partials which precedes AV in-stream)
  //  - lsepart: lm_head LSE partials in wt_qkv (dead after layer loop)
  //  - pp: proj split-K fp32 partials in w_bf[0:16MB] (w_bf consumed by AV
  //    before proj runs); consumed by ln_fuse(ln2) before FF1
  //  - fp: FF2 split-K fp32 partials in w_bf[16:32MB]; consumed by next
  //    layer's ln_fuse(ln1) / lnf BEFORE the next QK^T rewrites w_bf
  float2* smpart = (float2*)attb_bf;
  float2* lsepart = (float2*)wt_qkv;
  float* pp = (float*)w_bf;
  float* fp = (float*)w_bf + 2L * 2048 * DD;
  const long RES_PART = (long)2048 * DD;
  const int LSE_PN = (VV + 127) / 128;   // 393

  const dim3 blk(256);

  // --- weight prep: fp32 [K,N] -> bf16 [N,K], all layers per launch ---
  transpose_bf16_kernel<<<dim3(3 * DD / 32, DD / 32, LL), blk, 0, stream>>>(
      qkv_w, wt_qkv, DD, 3 * DD, (long)DD * 3 * DD, (long)DD * 3 * DD);
  transpose_bf16_kernel<<<dim3(DD / 32, DD / 32, LL), blk, 0, stream>>>(
      proj_w, wt_proj, DD, DD, (long)DD * DD, (long)DD * DD);
  transpose_bf16_kernel<<<dim3(DFF / 32, DD / 32, LL), blk, 0, stream>>>(
      w1, wt_w1, DD, DFF, (long)DD * DFF, (long)DD * DFF);
  transpose_bf16_kernel<<<dim3(DD / 32, DFF / 32, LL), blk, 0, stream>>>(
      w2, wt_w2, DFF, DD, (long)DFF * DD, (long)DFF * DD);
  convert_bf16_kernel<<<VV, blk, 0, stream>>>(emb, emb_bf);

  embed_kernel<<<BB * TT, blk, 0, stream>>>(idx, emb, pos_emb, x);
  zero_acc_kernel<<<1, 64, 0, stream>>>(accs);

  // all 4 layers' dists upfront (batched)
  dists_kernel<<<dim3(TT, 1, LL), blk, 0, stream>>>(positions, out + ALLD_OFF, accs + 2);

  for (int l = 0; l < LL; ++l) {
    float* allw_l = out + ALLW_OFF + (long)l * ALLW_STRIDE;
    float* alld_l = out + ALLD_OFF + (long)l * ALLD_STRIDE;

    if (l == 0)
      ln_kernel<<<BB * TT, blk, 0, stream>>>(x, ln1_g, ln1_b, h_bf);
    else
      ln_fuse_kernel<<<BB * TT, blk, 0, stream>>>(x, fp, fp + RES_PART,
          b2 + (long)(l - 1) * DD, ln1_g + l * DD, ln1_b + l * DD, h_bf);

    { GemmArgs ga = {}; ga.A = h_bf; ga.B = wt_qkv + (long)l * 3 * DD * DD;
      ga.M = BB * TT; ga.N = 3 * DD; ga.K = DD;
      ga.q = q_bf; ga.kk = k_bf; ga.vt = vt_bf; ga.mfirst = 1;
      gemm_kernel<EPI_QKV><<<dim3(16, 24, 1), blk, 0, stream>>>(ga); }

    // QK^T: lower-triangular 128x128 blocks only (36 of 64); raw S -> bf16 w_bf
    { GemmArgs ga = {}; ga.A = q_bf; ga.B = k_bf;
      ga.aBatch = (long)TT * DHH; ga.bBatch = (long)TT * DHH;
      ga.M = TT; ga.N = TT; ga.K = DHH;
      ga.outB = w_bf;
      gemm_kernel<EPI_SBF><<<dim3(36, 1, BB * HH), blk, 0, stream>>>(ga); }

    softmax_kernel<<<BB * HH * TT, blk, 0, stream>>>(w_bf, alld_l, allw_l, smpart);
    reduce_partials_kernel<<<64, blk, 0, stream>>>(smpart, BB * HH * TT, accs + 0, accs + 1);

    // AV: causal K-clamp (kend = bm+128) inside the kernel
    { GemmArgs ga = {}; ga.A = w_bf; ga.B = vt_bf;
      ga.aBatch = (long)TT * TT; ga.bBatch = (long)DHH * TT;
      ga.M = TT; ga.N = DHH; ga.K = TT;
      ga.outB = attb_bf;
      gemm_kernel<EPI_ATT><<<dim3(1, 8, BB * HH), blk, 0, stream>>>(ga); }

    // proj: split-K=2 fp32 partials (no atomics); reduce fused into ln2
    { GemmArgs ga = {}; ga.A = attb_bf; ga.B = wt_proj + (long)l * DD * DD;
      ga.M = BB * TT; ga.N = DD; ga.K = DD; ga.ldc = DD;
      ga.outF = pp; ga.cBatch = RES_PART; ga.kchunk = DD / 2; ga.mfirst = 1;
      gemm_kernel<EPI_F32><<<dim3(16, 8, 2), blk, 0, stream>>>(ga); }

    ln_fuse_kernel<<<BB * TT, blk, 0, stream>>>(x, pp, pp + RES_PART,
        nullptr, ln2_g + l * DD, ln2_b + l * DD, h_bf);

    { GemmArgs ga = {}; ga.A = h_bf; ga.B = wt_w1 + (long)l * DFF * DD;
      ga.M = BB * TT; ga.N = DFF; ga.K = DD;
      ga.bias = b1 + (long)l * DFF; ga.outB = g_bf; ga.mfirst = 1;
      gemm_kernel<EPI_GELU><<<dim3(16, 32, 1), blk, 0, stream>>>(ga); }

    // FF2: split-K=2 fp32 partials; reduce (+b2) fused into next ln1 / lnf
    { GemmArgs ga = {}; ga.A = g_bf; ga.B = wt_w2 + (long)l * DD * DFF;
      ga.M = BB * TT; ga.N = DD; ga.K = DFF; ga.ldc = DD;
      ga.outF = fp; ga.cBatch = RES_PART; ga.kchunk = DFF / 2; ga.mfirst = 1;
      gemm_kernel<EPI_F32><<<dim3(16, 8, 2), blk, 0, stream>>>(ga); }
  }

  ln_fuse_kernel<<<BB * TT, blk, 0, stream>>>(x, fp, fp + RES_PART,
      b2 + (long)(LL - 1) * DD, lnf_g, lnf_b, h_bf);

  // lm_head: M-fastest ordering -> 16 consecutive blocks share one 256KB
  // B-panel (L2-resident) instead of streaming 103MB emb_bf per M-row.
  { GemmArgs ga = {}; ga.A = h_bf; ga.B = emb_bf;
    ga.M = BB * TT; ga.N = VV; ga.K = DD;
    ga.outF = out; ga.ldc = VV; ga.cBatch = 0;
    ga.lsePart = lsepart; ga.pn = LSE_PN; ga.mfirst = 1;
    gemm_kernel<EPI_LSE><<<dim3(16, LSE_PN, 1), blk, 0, stream>>>(ga); }

  ce_reduce_kernel<<<BB * TT, blk, 0, stream>>>(lsepart, out, targets, accs + 3, LSE_PN);
  finalize_kernel<<<1, 64, 0, stream>>>(accs, out + SCAL_OFF);
}

// Round 8
// 2637.540 us; speedup vs baseline: 1.0149x; 1.0149x over previous
//
#include <hip/hip_runtime.h>
#include <hip/hip_bf16.h>
#include <cmath>

#define TT 1024
#define DD 1024
#define HH 16
#define LL 4
#define BB 2
#define DHH 64
#define DFF 4096
#define VV 50257

typedef float floatx4 __attribute__((ext_vector_type(4)));
typedef __bf16 bf16x8 __attribute__((ext_vector_type(8)));

typedef unsigned int u32;
typedef __attribute__((address_space(1))) const u32 gu32;
typedef __attribute__((address_space(3))) u32 lu32;

__device__ __forceinline__ void gload16(const unsigned short* g, unsigned short* l) {
  __builtin_amdgcn_global_load_lds((gu32*)g, (lu32*)l, 16, 0, 0);
}

__device__ __forceinline__ unsigned short f2bf(float f) {
  unsigned u = __float_as_uint(f);
  u += 0x7fffu + ((u >> 16) & 1u);
  return (unsigned short)(u >> 16);
}
__device__ __forceinline__ float bf2f(unsigned short u) {
  return __uint_as_float(((unsigned)u) << 16);
}

__device__ __forceinline__ float wave_sum(float v) {
#pragma unroll
  for (int off = 1; off < 64; off <<= 1) v += __shfl_xor(v, off);
  return v;
}
__device__ __forceinline__ float wave_max(float v) {
#pragma unroll
  for (int off = 1; off < 64; off <<= 1) v = fmaxf(v, __shfl_xor(v, off));
  return v;
}

// ---------------- GEMM: C = A[M,K] * B[N,K]^T, bf16 inputs, fp32 acc ----------------
#define EPI_F32 0   // fp32 store (also split-K partials via kchunk)
#define EPI_QKV 1
#define EPI_GELU 3
#define EPI_LSE 4
#define EPI_SBF 5   // bf16 raw-S store, lower-triangular block grid

struct GemmArgs {
  const unsigned short* A;
  const unsigned short* B;
  long aBatch, bBatch, cBatch;
  int M, N, K, ldc;
  float* outF;               // EPI_F32 / EPI_LSE
  unsigned short* q;         // EPI_QKV
  unsigned short* kk;
  unsigned short* vt;
  unsigned short* outB;      // EPI_GELU / EPI_SBF
  const float* bias;         // EPI_GELU
  float2* lsePart;           // EPI_LSE per-(row,block) partials
  int pn;                    // EPI_LSE: N-block count
  int kchunk;                // split-K: K per z-split (0 = no split, z = batch)
};

template <int EPI>
__global__ __launch_bounds__(256) void gemm_kernel(GemmArgs ga) {
  __shared__ __align__(16) unsigned short As[128 * 32];
  __shared__ __align__(16) unsigned short Bs[128 * 32];
  const int tid = threadIdx.x;
  int bm, bn;
  if constexpr (EPI == EPI_SBF) {
    // packed lower-triangular block index -> (r,c), r >= c
    const int xb = blockIdx.x;
    int r = (int)((sqrtf(8.f * xb + 1.f) - 1.f) * 0.5f);
    if ((r * (r + 1)) / 2 > xb) --r;
    else if (((r + 1) * (r + 2)) / 2 <= xb) ++r;
    const int c = xb - (r * (r + 1)) / 2;
    bm = r * 128; bn = c * 128;
  } else {
    bm = blockIdx.y * 128; bn = blockIdx.x * 128;
  }
  const int z = blockIdx.z;
  const unsigned short* A = ga.A + (long)z * ga.aBatch;
  const unsigned short* Bp = ga.B + (long)z * ga.bBatch;
  const int K = ga.K, N = ga.N;

  int kbeg = 0, kend = K;
  if (ga.kchunk) { kbeg = z * ga.kchunk; kend = kbeg + ga.kchunk; }

  floatx4 acc[4][4];
#pragma unroll
  for (int i = 0; i < 4; ++i)
#pragma unroll
    for (int j = 0; j < 4; ++j) acc[i][j] = (floatx4){0.f, 0.f, 0.f, 0.f};

  const int lane = tid & 63, wave = tid >> 6;
  const int wm = (wave & 1) * 64, wn = (wave >> 1) * 64;
  const int fr = lane & 15, quad = lane >> 4;
  const int srow = tid >> 2;
  const int sc8 = (tid & 3) * 8;

  // LDS dest is wave-uniform base + lane*16B; layout is exactly lane-linear.
  unsigned short* lA0 = &As[wave * 512];
  unsigned short* lA1 = &As[2048 + wave * 512];
  unsigned short* lB0 = &Bs[wave * 512];
  unsigned short* lB1 = &Bs[2048 + wave * 512];

  for (int k0 = kbeg; k0 < kend; k0 += 32) {
    const long ra = (long)(bm + srow) * K + (k0 + sc8);
    const long rb = (long)(bn + srow) * K + (k0 + sc8);
    gload16(A + ra, lA0);
    gload16(A + ra + 64L * K, lA1);
    gload16(Bp + rb, lB0);
    gload16(Bp + rb + 64L * K, lB1);
    __syncthreads();
    bf16x8 af[4], bfr[4];
#pragma unroll
    for (int i = 0; i < 4; ++i) af[i] = *(const bf16x8*)(&As[(wm + i * 16 + fr) * 32 + quad * 8]);
#pragma unroll
    for (int j = 0; j < 4; ++j) bfr[j] = *(const bf16x8*)(&Bs[(wn + j * 16 + fr) * 32 + quad * 8]);
#pragma unroll
    for (int i = 0; i < 4; ++i)
#pragma unroll
      for (int j = 0; j < 4; ++j)
        acc[i][j] = __builtin_amdgcn_mfma_f32_16x16x32_bf16(af[i], bfr[j], acc[i][j], 0, 0, 0);
    __syncthreads();
  }

  if constexpr (EPI == EPI_LSE) {
    // store logits + per-row (max, sumexp) partial; two-pass, no dependent exp chains
    float2* sm = (float2*)As;
#pragma unroll
    for (int i = 0; i < 4; ++i) {
#pragma unroll
      for (int r = 0; r < 4; ++r) {
        const int m = bm + wm + i * 16 + quad * 4 + r;
        float mx = -INFINITY;
#pragma unroll
        for (int j = 0; j < 4; ++j) {
          const int n = bn + wn + j * 16 + fr;
          if (n < N) {
            const float val = acc[i][j][r];
            __builtin_nontemporal_store(val, &ga.outF[(long)m * ga.ldc + n]);
            mx = fmaxf(mx, val);
          }
        }
#pragma unroll
        for (int off = 1; off < 16; off <<= 1) mx = fmaxf(mx, __shfl_xor(mx, off));
        float ss = 0.f;
#pragma unroll
        for (int j = 0; j < 4; ++j) {
          const int n = bn + wn + j * 16 + fr;
          if (n < N) ss += __expf(acc[i][j][r] - mx);
        }
#pragma unroll
        for (int off = 1; off < 16; off <<= 1) ss += __shfl_xor(ss, off);
        if (fr == 0) {
          const int rl = wm + i * 16 + quad * 4 + r;
          sm[rl * 2 + (wave >> 1)] = make_float2(mx, ss);
        }
      }
    }
    __syncthreads();
    if (tid < 128) {
      const float2 a = sm[tid * 2], b = sm[tid * 2 + 1];
      const float M = fmaxf(a.x, b.x);
      const float S = a.y * __expf(a.x - M) + b.y * __expf(b.x - M);
      ga.lsePart[(long)(bm + tid) * ga.pn + blockIdx.x] = make_float2(M, S);
    }
  } else {
#pragma unroll
    for (int i = 0; i < 4; ++i) {
#pragma unroll
      for (int j = 0; j < 4; ++j) {
        const int n = bn + wn + j * 16 + fr;
#pragma unroll
        for (int r = 0; r < 4; ++r) {
          const int m = bm + wm + i * 16 + quad * 4 + r;
          const float val = acc[i][j][r];
          if constexpr (EPI == EPI_F32) {
            if (n < N) ga.outF[(long)z * ga.cBatch + (long)m * ga.ldc + n] = val;
          }
          if constexpr (EPI == EPI_SBF) {
            ga.outB[(long)z * TT * TT + (long)m * TT + n] = f2bf(val);
          }
          if constexpr (EPI == EPI_QKV) {
            const int b = m >> 10, t = m & 1023;
            const int sec = n >> 10, col = n & 1023;
            const int hd = col >> 6, dh = col & 63;
            const unsigned short bv = f2bf(val);
            if (sec == 0)      ga.q [((long)(b * HH + hd) * TT + t) * DHH + dh] = bv;
            else if (sec == 1) ga.kk[((long)(b * HH + hd) * TT + t) * DHH + dh] = bv;
            else               ga.vt[((long)(b * HH + hd) * DHH + dh) * TT + t] = bv;
          }
          if constexpr (EPI == EPI_GELU) {
            const float xx = val + ga.bias[n];
            const float gl = 0.5f * xx * (1.f + erff(xx * 0.7071067811865475f));
            ga.outB[(long)m * DFF + n] = f2bf(gl);
          }
        }
      }
    }
  }
}

// ---------- AV GEMM: att = w[T,T] x vt[64,T]^T, 128x64 tiles (no wasted MFMA) ----------
// 4 waves stacked on M (wm = wave*32, acc[2][4]); causal K-clamp kend = bm+128.
__global__ __launch_bounds__(256) void gemm_av_kernel(
    const unsigned short* __restrict__ W, const unsigned short* __restrict__ Vt,
    unsigned short* __restrict__ outB) {
  __shared__ __align__(16) unsigned short As[128 * 32];  // 8 KB
  __shared__ __align__(16) unsigned short Bs[64 * 32];   // 4 KB
  const int tid = threadIdx.x;
  const int bm = blockIdx.y * 128;
  const int z = blockIdx.z;
  const unsigned short* A = W + (long)z * TT * TT;
  const unsigned short* Bp = Vt + (long)z * DHH * TT;
  const int lane = tid & 63, wave = tid >> 6;
  const int fr = lane & 15, quad = lane >> 4;
  const int wm = wave * 32;
  const int srow = tid >> 2;          // 0..63
  const int sc8 = (tid & 3) * 8;

  floatx4 acc[2][4];
#pragma unroll
  for (int i = 0; i < 2; ++i)
#pragma unroll
    for (int j = 0; j < 4; ++j) acc[i][j] = (floatx4){0.f, 0.f, 0.f, 0.f};

  unsigned short* lA0 = &As[wave * 512];
  unsigned short* lA1 = &As[2048 + wave * 512];
  unsigned short* lB0 = &Bs[wave * 512];

  const int kend = bm + 128;  // w[m,k]==0 for k>m (exact zeros from softmax)
  for (int k0 = 0; k0 < kend; k0 += 32) {
    const long ra = (long)(bm + srow) * TT + (k0 + sc8);
    gload16(A + ra, lA0);
    gload16(A + ra + 64L * TT, lA1);
    gload16(Bp + (long)srow * TT + (k0 + sc8), lB0);  // V rows 0..63 only
    __syncthreads();
    bf16x8 af[2], bfr[4];
#pragma unroll
    for (int i = 0; i < 2; ++i) af[i] = *(const bf16x8*)(&As[(wm + i * 16 + fr) * 32 + quad * 8]);
#pragma unroll
    for (int j = 0; j < 4; ++j) bfr[j] = *(const bf16x8*)(&Bs[(j * 16 + fr) * 32 + quad * 8]);
#pragma unroll
    for (int i = 0; i < 2; ++i)
#pragma unroll
      for (int j = 0; j < 4; ++j)
        acc[i][j] = __builtin_amdgcn_mfma_f32_16x16x32_bf16(af[i], bfr[j], acc[i][j], 0, 0, 0);
    __syncthreads();
  }

  const int b = z >> 4, hd = z & 15;
#pragma unroll
  for (int i = 0; i < 2; ++i) {
#pragma unroll
    for (int j = 0; j < 4; ++j) {
      const int n = j * 16 + fr;
#pragma unroll
      for (int r = 0; r < 4; ++r) {
        const int m = bm + wm + i * 16 + quad * 4 + r;
        outB[((long)(b * TT + m)) * DD + hd * DHH + n] = f2bf(acc[i][j][r]);
      }
    }
  }
}

// -------- transpose fp32 [R,C] -> bf16 [C,R], layer-batched via blockIdx.z --------
__global__ __launch_bounds__(256) void transpose_bf16_kernel(const float* __restrict__ src0,
    unsigned short* __restrict__ dst0, int R, int C, long sStride, long dStride) {
  const float* src = src0 + (long)blockIdx.z * sStride;
  unsigned short* dst = dst0 + (long)blockIdx.z * dStride;
  __shared__ float tile[32][33];
  const int c0 = blockIdx.x * 32, r0 = blockIdx.y * 32;
  const int tx = threadIdx.x & 31, ty = threadIdx.x >> 5;
#pragma unroll
  for (int rr = ty; rr < 32; rr += 8)
    tile[rr][tx] = src[(long)(r0 + rr) * C + (c0 + tx)];
  __syncthreads();
#pragma unroll
  for (int rr = ty; rr < 32; rr += 8)
    dst[(long)(c0 + rr) * R + (r0 + tx)] = f2bf(tile[tx][rr]);
}

__global__ __launch_bounds__(256) void convert_bf16_kernel(const float* __restrict__ in,
    unsigned short* __restrict__ out) {
  const long i = (long)blockIdx.x * 256 + threadIdx.x;
  const float4 v = ((const float4*)in)[i];
  ushort4 o;
  o.x = f2bf(v.x); o.y = f2bf(v.y); o.z = f2bf(v.z); o.w = f2bf(v.w);
  ((ushort4*)out)[i] = o;
}

__global__ __launch_bounds__(256) void embed_kernel(const int* __restrict__ idx,
    const float* __restrict__ emb, const float* __restrict__ pos, float* __restrict__ x) {
  const int bt = blockIdx.x;
  const int t = bt & (TT - 1);
  const int tok = idx[bt];
  const float4 e = ((const float4*)(emb + (long)tok * DD))[threadIdx.x];
  const float4 p = ((const float4*)(pos + (long)t * DD))[threadIdx.x];
  float4 o; o.x = e.x + p.x; o.y = e.y + p.y; o.z = e.z + p.z; o.w = e.w + p.w;
  ((float4*)(x + (long)bt * DD))[threadIdx.x] = o;
}

__global__ __launch_bounds__(256) void ln_kernel(const float* __restrict__ x,
    const float* __restrict__ g, const float* __restrict__ b, unsigned short* __restrict__ out) {
  const int row = blockIdx.x;
  const float4 v = ((const float4*)(x + (long)row * DD))[threadIdx.x];
  float s = v.x + v.y + v.z + v.w;
  float s2 = v.x * v.x + v.y * v.y + v.z * v.z + v.w * v.w;
  s = wave_sum(s); s2 = wave_sum(s2);
  __shared__ float ps[4], ps2[4];
  const int wv = threadIdx.x >> 6, lane = threadIdx.x & 63;
  if (lane == 0) { ps[wv] = s; ps2[wv] = s2; }
  __syncthreads();
  s = ps[0] + ps[1] + ps[2] + ps[3];
  s2 = ps2[0] + ps2[1] + ps2[2] + ps2[3];
  const float mean = s * (1.f / DD);
  const float var = s2 * (1.f / DD) - mean * mean;
  const float rs = rsqrtf(var + 1e-5f);
  const float4 gv = ((const float4*)g)[threadIdx.x];
  const float4 bv = ((const float4*)b)[threadIdx.x];
  ushort4 o;
  o.x = f2bf((v.x - mean) * rs * gv.x + bv.x);
  o.y = f2bf((v.y - mean) * rs * gv.y + bv.y);
  o.z = f2bf((v.z - mean) * rs * gv.z + bv.z);
  o.w = f2bf((v.w - mean) * rs * gv.w + bv.w);
  ((ushort4*)(out + (long)row * DD))[threadIdx.x] = o;
}

__global__ __launch_bounds__(256) void ln_fuse_kernel(float* __restrict__ x,
    const float* __restrict__ p0, const float* __restrict__ p1,
    const float* __restrict__ bias,
    const float* __restrict__ g, const float* __restrict__ b,
    unsigned short* __restrict__ out) {
  const int row = blockIdx.x;
  float4 v = ((const float4*)(x + (long)row * DD))[threadIdx.x];
  const float4 a0 = ((const float4*)(p0 + (long)row * DD))[threadIdx.x];
  const float4 a1 = ((const float4*)(p1 + (long)row * DD))[threadIdx.x];
  v.x += a0.x + a1.x; v.y += a0.y + a1.y; v.z += a0.z + a1.z; v.w += a0.w + a1.w;
  if (bias) {
    const float4 bb = ((const float4*)bias)[threadIdx.x];
    v.x += bb.x; v.y += bb.y; v.z += bb.z; v.w += bb.w;
  }
  ((float4*)(x + (long)row * DD))[threadIdx.x] = v;
  float s = v.x + v.y + v.z + v.w;
  float s2 = v.x * v.x + v.y * v.y + v.z * v.z + v.w * v.w;
  s = wave_sum(s); s2 = wave_sum(s2);
  __shared__ float ps[4], ps2[4];
  const int wv = threadIdx.x >> 6, lane = threadIdx.x & 63;
  if (lane == 0) { ps[wv] = s; ps2[wv] = s2; }
  __syncthreads();
  s = ps[0] + ps[1] + ps[2] + ps[3];
  s2 = ps2[0] + ps2[1] + ps2[2] + ps2[3];
  const float mean = s * (1.f / DD);
  const float var = s2 * (1.f / DD) - mean * mean;
  const float rs = rsqrtf(var + 1e-5f);
  const float4 gv = ((const float4*)g)[threadIdx.x];
  const float4 bv = ((const float4*)b)[threadIdx.x];
  ushort4 o;
  o.x = f2bf((v.x - mean) * rs * gv.x + bv.x);
  o.y = f2bf((v.y - mean) * rs * gv.y + bv.y);
  o.z = f2bf((v.z - mean) * rs * gv.z + bv.z);
  o.w = f2bf((v.w - mean) * rs * gv.w + bv.w);
  ((ushort4*)(out + (long)row * DD))[threadIdx.x] = o;
}

// all layers batched via blockIdx.z
__global__ __launch_bounds__(256) void dists_kernel(const float* __restrict__ pos0,
    float* __restrict__ dout0, float* __restrict__ tre_acc) {
  const float* pos = pos0 + (long)blockIdx.z * TT * 3;
  float* dout = dout0 + (long)blockIdx.z * TT * TT;
  const int i = blockIdx.x;
  const float px = pos[i * 3], py = pos[i * 3 + 1], pz = pos[i * 3 + 2];
  float rsum = 0.f;
#pragma unroll
  for (int c = 0; c < 4; ++c) {
    const int j = c * 256 + threadIdx.x;
    const float dx = px - pos[j * 3];
    const float dy = py - pos[j * 3 + 1];
    const float dz = pz - pos[j * 3 + 2];
    const float sq = dx * dx + dy * dy + dz * dz;
    const float d = sq > 0.f ? sqrtf(sq) : 0.f;
    dout[(long)i * TT + j] = d;
    if (j != i) rsum += 1.f / (d + 1e-4f);
  }
  rsum = wave_sum(rsum);
  __shared__ float ps[4];
  const int wv = threadIdx.x >> 6, lane = threadIdx.x & 63;
  if (lane == 0) ps[wv] = rsum;
  __syncthreads();
  if (threadIdx.x == 0) atomicAdd(tre_acc, ps[0] + ps[1] + ps[2] + ps[3]);
}

__global__ __launch_bounds__(256) void softmax_kernel(unsigned short* __restrict__ wb,
    const float* __restrict__ dists, float* __restrict__ W,
    float2* __restrict__ partials) {
  const long row = blockIdx.x;
  const int i = (int)(row & (TT - 1));
  unsigned short* sr = wb + row * TT;
  const float* dr = dists + (long)i * TT;
  const int j0 = threadIdx.x * 4;

  const float4 dv = ((const float4*)dr)[threadIdx.x];
  const ushort4 su = ((const ushort4*)sr)[threadIdx.x];
  float d[4] = {dv.x, dv.y, dv.z, dv.w};
  float sa[4] = {bf2f(su.x), bf2f(su.y), bf2f(su.z), bf2f(su.w)};
  float l[4];
  float mx = -INFINITY;
#pragma unroll
  for (int c = 0; c < 4; ++c) {
    float v = sa[c] * 0.125f - d[c];
    if (j0 + c > i) v = -INFINITY;
    l[c] = v;
    mx = fmaxf(mx, v);
  }
  mx = wave_max(mx);
  __shared__ float rmax[4], rsm[4], rwd[4], rent[4];
  const int wv = threadIdx.x >> 6, lane = threadIdx.x & 63;
  if (lane == 0) rmax[wv] = mx;
  __syncthreads();
  mx = fmaxf(fmaxf(rmax[0], rmax[1]), fmaxf(rmax[2], rmax[3]));
  float e[4], sum = 0.f;
#pragma unroll
  for (int c = 0; c < 4; ++c) { e[c] = __expf(l[c] - mx); sum += e[c]; }
  sum = wave_sum(sum);
  if (lane == 0) rsm[wv] = sum;
  __syncthreads();
  sum = rsm[0] + rsm[1] + rsm[2] + rsm[3];
  const float inv = 1.f / sum;
  floatx4 wo;
  ushort4 bo;
  const float w0 = e[0] * inv, w1 = e[1] * inv, w2 = e[2] * inv, w3 = e[3] * inv;
  wo[0] = w0; wo[1] = w1; wo[2] = w2; wo[3] = w3;
  bo.x = f2bf(w0); bo.y = f2bf(w1); bo.z = f2bf(w2); bo.w = f2bf(w3);
  float wd = w0 * d[0] + w1 * d[1] + w2 * d[2] + w3 * d[3];
  float ent = -(w0 * __logf(w0 + 1e-9f) + w1 * __logf(w1 + 1e-9f)
        + w2 * __logf(w2 + 1e-9f) + w3 * __logf(w3 + 1e-9f));
  __builtin_nontemporal_store(wo, (floatx4*)(W + row * TT) + threadIdx.x);
  ((ushort4*)sr)[threadIdx.x] = bo;
  wd = wave_sum(wd); ent = wave_sum(ent);
  if (lane == 0) { rwd[wv] = wd; rent[wv] = ent; }
  __syncthreads();
  if (threadIdx.x == 0) {
    partials[row] = make_float2(rwd[0] + rwd[1] + rwd[2] + rwd[3],
                                rent[0] + rent[1] + rent[2] + rent[3]);
  }
}

__global__ __launch_bounds__(256) void reduce_partials_kernel(const float2* __restrict__ p,
    int n, float* __restrict__ tde_acc, float* __restrict__ tfe_acc) {
  float wd = 0.f, ent = 0.f;
  for (int i = blockIdx.x * 256 + threadIdx.x; i < n; i += gridDim.x * 256) {
    const float2 v = p[i];
    wd += v.x; ent += v.y;
  }
  wd = wave_sum(wd); ent = wave_sum(ent);
  __shared__ float pw[4], pe[4];
  const int wv = threadIdx.x >> 6, lane = threadIdx.x & 63;
  if (lane == 0) { pw[wv] = wd; pe[wv] = ent; }
  __syncthreads();
  if (threadIdx.x == 0) {
    atomicAdd(tde_acc, pw[0] + pw[1] + pw[2] + pw[3]);
    atomicAdd(tfe_acc, pe[0] + pe[1] + pe[2] + pe[3]);
  }
}

__global__ __launch_bounds__(256) void ce_reduce_kernel(const float2* __restrict__ part,
    const float* __restrict__ logits, const int* __restrict__ targets,
    float* __restrict__ ce_acc, int pn) {
  const int row = blockIdx.x;
  const float2* pr = part + (long)row * pn;
  float m = -INFINITY, s = 0.f;
  for (int i = threadIdx.x; i < pn; i += 256) {
    const float2 v = pr[i];
    const float M = fmaxf(m, v.x);
    s = s * __expf(m - M) + v.y * __expf(v.x - M);
    m = M;
  }
#pragma unroll
  for (int off = 1; off < 64; off <<= 1) {
    const float mo = __shfl_xor(m, off), so = __shfl_xor(s, off);
    const float M = fmaxf(m, mo);
    s = s * __expf(m - M) + so * __expf(mo - M);
    m = M;
  }
  __shared__ float pm[4], psv[4];
  const int wv = threadIdx.x >> 6, lane = threadIdx.x & 63;
  if (lane == 0) { pm[wv] = m; psv[wv] = s; }
  __syncthreads();
  if (threadIdx.x == 0) {
    const float M = fmaxf(fmaxf(pm[0], pm[1]), fmaxf(pm[2], pm[3]));
    const float S = psv[0] * __expf(pm[0] - M) + psv[1] * __expf(pm[1] - M)
                  + psv[2] * __expf(pm[2] - M) + psv[3] * __expf(pm[3] - M);
    atomicAdd(ce_acc, M + logf(S) - logits[(long)row * VV + targets[row]]);
  }
}

__global__ void zero_acc_kernel(float* p) { if (threadIdx.x < 4) p[threadIdx.x] = 0.f; }

__global__ void finalize_kernel(const float* __restrict__ acc, float* __restrict__ o) {
  if (threadIdx.x == 0) {
    const float tde = acc[0] * (1.f / 32768.f);
    const float tfe = acc[1] * (1.f / 32768.f);
    const float tre = acc[2] * (1.f / 1047552.f);
    const float ce = acc[3] * (1.f / 2048.f);
    o[0] = ce + 0.01f * tde + 0.1f * tfe + 0.01f * tre;
    o[1] = tde; o[2] = tfe; o[3] = tre;
  }
}

extern "C" void kernel_launch(void* const* d_in, const int* in_sizes, int n_in,
                              void* d_out, int out_size, void* d_ws, size_t ws_size,
                              hipStream_t stream) {
  const int* idx = (const int*)d_in[0];
  const int* targets = (const int*)d_in[1];
  const float* emb = (const float*)d_in[2];
  const float* pos_emb = (const float*)d_in[3];
  const float* positions = (const float*)d_in[4];
  const float* ln1_g = (const float*)d_in[5];
  const float* ln1_b = (const float*)d_in[6];
  const float* ln2_g = (const float*)d_in[7];
  const float* ln2_b = (const float*)d_in[8];
  const float* lnf_g = (const float*)d_in[9];
  const float* lnf_b = (const float*)d_in[10];
  const float* qkv_w = (const float*)d_in[11];
  const float* proj_w = (const float*)d_in[12];
  const float* w1 = (const float*)d_in[13];
  const float* b1 = (const float*)d_in[14];
  const float* w2 = (const float*)d_in[15];
  const float* b2 = (const float*)d_in[16];

  float* out = (float*)d_out;
  char* ws = (char*)d_ws;

  const long LOGITS_N = (long)BB * TT * VV;
  const long SCAL_OFF = LOGITS_N;
  const long ALLW_OFF = LOGITS_N + 4;
  const long ALLW_STRIDE = (long)BB * HH * TT * TT;
  const long ALLD_OFF = ALLW_OFF + 4 * ALLW_STRIDE;

  unsigned short* wt_qkv  = (unsigned short*)(ws);
  unsigned short* wt_proj = (unsigned short*)(ws + 25165824L);
  unsigned short* wt_w1   = (unsigned short*)(ws + 33554432L);
  unsigned short* wt_w2   = (unsigned short*)(ws + 67108864L);
  unsigned short* emb_bf  = (unsigned short*)(ws + 100663296L);
  float*          x       = (float*)(ws + 203589632L);
  unsigned short* h_bf    = (unsigned short*)(ws + 211978240L);
  unsigned short* q_bf    = (unsigned short*)(ws + 216172544L);
  unsigned short* k_bf    = (unsigned short*)(ws + 220366848L);
  unsigned short* vt_bf   = (unsigned short*)(ws + 224561152L);
  unsigned short* attb_bf = (unsigned short*)(ws + 228755456L);
  unsigned short* g_bf    = (unsigned short*)(ws + 232949760L);
  unsigned short* w_bf    = (unsigned short*)(ws + 249726976L);
  float*          accs    = (float*)(ws + 316835840L);

  // scratch overlays (lifetime-checked; see R3 notes)
  float2* smpart = (float2*)attb_bf;
  float2* lsepart = (float2*)wt_qkv;
  float* pp = (float*)w_bf;
  float* fp = (float*)w_bf + 2L * 2048 * DD;
  const long RES_PART = (long)2048 * DD;
  const int LSE_PN = (VV + 127) / 128;   // 393

  const dim3 blk(256);

  transpose_bf16_kernel<<<dim3(3 * DD / 32, DD / 32, LL), blk, 0, stream>>>(
      qkv_w, wt_qkv, DD, 3 * DD, (long)DD * 3 * DD, (long)DD * 3 * DD);
  transpose_bf16_kernel<<<dim3(DD / 32, DD / 32, LL), blk, 0, stream>>>(
      proj_w, wt_proj, DD, DD, (long)DD * DD, (long)DD * DD);
  transpose_bf16_kernel<<<dim3(DFF / 32, DD / 32, LL), blk, 0, stream>>>(
      w1, wt_w1, DD, DFF, (long)DD * DFF, (long)DD * DFF);
  transpose_bf16_kernel<<<dim3(DD / 32, DFF / 32, LL), blk, 0, stream>>>(
      w2, wt_w2, DFF, DD, (long)DFF * DD, (long)DFF * DD);
  convert_bf16_kernel<<<VV, blk, 0, stream>>>(emb, emb_bf);

  embed_kernel<<<BB * TT, blk, 0, stream>>>(idx, emb, pos_emb, x);
  zero_acc_kernel<<<1, 64, 0, stream>>>(accs);

  dists_kernel<<<dim3(TT, 1, LL), blk, 0, stream>>>(positions, out + ALLD_OFF, accs + 2);

  for (int l = 0; l < LL; ++l) {
    float* allw_l = out + ALLW_OFF + (long)l * ALLW_STRIDE;
    float* alld_l = out + ALLD_OFF + (long)l * (long)TT * TT;

    if (l == 0)
      ln_kernel<<<BB * TT, blk, 0, stream>>>(x, ln1_g, ln1_b, h_bf);
    else
      ln_fuse_kernel<<<BB * TT, blk, 0, stream>>>(x, fp, fp + RES_PART,
          b2 + (long)(l - 1) * DD, ln1_g + l * DD, ln1_b + l * DD, h_bf);

    { GemmArgs ga = {}; ga.A = h_bf; ga.B = wt_qkv + (long)l * 3 * DD * DD;
      ga.M = BB * TT; ga.N = 3 * DD; ga.K = DD;
      ga.q = q_bf; ga.kk = k_bf; ga.vt = vt_bf;
      gemm_kernel<EPI_QKV><<<dim3(24, 16, 1), blk, 0, stream>>>(ga); }

    { GemmArgs ga = {}; ga.A = q_bf; ga.B = k_bf;
      ga.aBatch = (long)TT * DHH; ga.bBatch = (long)TT * DHH;
      ga.M = TT; ga.N = TT; ga.K = DHH;
      ga.outB = w_bf;
      gemm_kernel<EPI_SBF><<<dim3(36, 1, BB * HH), blk, 0, stream>>>(ga); }

    softmax_kernel<<<BB * HH * TT, blk, 0, stream>>>(w_bf, alld_l, allw_l, smpart);
    reduce_partials_kernel<<<64, blk, 0, stream>>>(smpart, BB * HH * TT, accs + 0, accs + 1);

    gemm_av_kernel<<<dim3(1, 8, BB * HH), blk, 0, stream>>>(w_bf, vt_bf, attb_bf);

    { GemmArgs ga = {}; ga.A = attb_bf; ga.B = wt_proj + (long)l * DD * DD;
      ga.M = BB * TT; ga.N = DD; ga.K = DD; ga.ldc = DD;
      ga.outF = pp; ga.cBatch = RES_PART; ga.kchunk = DD / 2;
      gemm_kernel<EPI_F32><<<dim3(8, 16, 2), blk, 0, stream>>>(ga); }

    ln_fuse_kernel<<<BB * TT, blk, 0, stream>>>(x, pp, pp + RES_PART,
        nullptr, ln2_g + l * DD, ln2_b + l * DD, h_bf);

    { GemmArgs ga = {}; ga.A = h_bf; ga.B = wt_w1 + (long)l * DFF * DD;
      ga.M = BB * TT; ga.N = DFF; ga.K = DD;
      ga.bias = b1 + (long)l * DFF; ga.outB = g_bf;
      gemm_kernel<EPI_GELU><<<dim3(32, 16, 1), blk, 0, stream>>>(ga); }

    { GemmArgs ga = {}; ga.A = g_bf; ga.B = wt_w2 + (long)l * DD * DFF;
      ga.M = BB * TT; ga.N = DD; ga.K = DFF; ga.ldc = DD;
      ga.outF = fp; ga.cBatch = RES_PART; ga.kchunk = DFF / 2;
      gemm_kernel<EPI_F32><<<dim3(8, 16, 2), blk, 0, stream>>>(ga); }
  }

  ln_fuse_kernel<<<BB * TT, blk, 0, stream>>>(x, fp, fp + RES_PART,
      b2 + (long)(LL - 1) * DD, lnf_g, lnf_b, h_bf);

  { GemmArgs ga = {}; ga.A = h_bf; ga.B = emb_bf;
    ga.M = BB * TT; ga.N = VV; ga.K = DD;
    ga.outF = out; ga.ldc = VV; ga.cBatch = 0;
    ga.lsePart = lsepart; ga.pn = LSE_PN;
    gemm_kernel<EPI_LSE><<<dim3(LSE_PN, 16, 1), blk, 0, stream>>>(ga); }

  ce_reduce_kernel<<<BB * TT, blk, 0, stream>>>(lsepart, out, targets, accs + 3, LSE_PN);
  finalize_kernel<<<1, 64, 0, stream>>>(accs, out + SCAL_OFF);
}

// Round 9
// 2598.544 us; speedup vs baseline: 1.0301x; 1.0150x over previous
//
#include <hip/hip_runtime.h>
#include <hip/hip_bf16.h>
#include <cmath>

#define TT 1024
#define DD 1024
#define HH 16
#define LL 4
#define BB 2
#define DHH 64
#define DFF 4096
#define VV 50257

typedef float floatx4 __attribute__((ext_vector_type(4)));
typedef __bf16 bf16x8 __attribute__((ext_vector_type(8)));

typedef unsigned int u32;
typedef __attribute__((address_space(1))) const u32 gu32;
typedef __attribute__((address_space(3))) u32 lu32;

__device__ __forceinline__ void gload16(const unsigned short* g, unsigned short* l) {
  __builtin_amdgcn_global_load_lds((gu32*)g, (lu32*)l, 16, 0, 0);
}

__device__ __forceinline__ unsigned short f2bf(float f) {
  unsigned u = __float_as_uint(f);
  u += 0x7fffu + ((u >> 16) & 1u);
  return (unsigned short)(u >> 16);
}
__device__ __forceinline__ float bf2f(unsigned short u) {
  return __uint_as_float(((unsigned)u) << 16);
}

__device__ __forceinline__ float wave_sum(float v) {
#pragma unroll
  for (int off = 1; off < 64; off <<= 1) v += __shfl_xor(v, off);
  return v;
}
__device__ __forceinline__ float wave_max(float v) {
#pragma unroll
  for (int off = 1; off < 64; off <<= 1) v = fmaxf(v, __shfl_xor(v, off));
  return v;
}

// ---------------- GEMM: C = A[M,K] * B[N,K]^T, bf16 inputs, fp32 acc ----------------
#define EPI_F32 0   // fp32 store (also split-K partials via kchunk)
#define EPI_QKV 1
#define EPI_GELU 3
#define EPI_LSE 4
#define EPI_SBF 5   // bf16 raw-S store, lower-triangular block grid

struct GemmArgs {
  const unsigned short* A;
  const unsigned short* B;
  long aBatch, bBatch, cBatch;
  int M, N, K, ldc;
  float* outF;               // EPI_F32 / EPI_LSE
  unsigned short* q;         // EPI_QKV
  unsigned short* kk;
  unsigned short* vt;
  unsigned short* outB;      // EPI_GELU / EPI_SBF
  const float* bias;         // EPI_GELU
  float2* lsePart;           // EPI_LSE per-(row,block) partials
  int pn;                    // EPI_LSE: N-block count
  int kchunk;                // split-K: K per z-split (0 = no split, z = batch)
};

template <int EPI>
__global__ __launch_bounds__(256) void gemm_kernel(GemmArgs ga) {
  __shared__ __align__(16) unsigned short As[128 * 32];
  __shared__ __align__(16) unsigned short Bs[128 * 32];
  const int tid = threadIdx.x;
  int bm, bn;
  if constexpr (EPI == EPI_SBF) {
    // packed lower-triangular block index -> (r,c), r >= c
    const int xb = blockIdx.x;
    int r = (int)((sqrtf(8.f * xb + 1.f) - 1.f) * 0.5f);
    if ((r * (r + 1)) / 2 > xb) --r;
    else if (((r + 1) * (r + 2)) / 2 <= xb) ++r;
    const int c = xb - (r * (r + 1)) / 2;
    bm = r * 128; bn = c * 128;
  } else {
    bm = blockIdx.y * 128; bn = blockIdx.x * 128;
  }
  const int z = blockIdx.z;
  const unsigned short* A = ga.A + (long)z * ga.aBatch;
  const unsigned short* Bp = ga.B + (long)z * ga.bBatch;
  const int K = ga.K, N = ga.N;

  int kbeg = 0, kend = K;
  if (ga.kchunk) { kbeg = z * ga.kchunk; kend = kbeg + ga.kchunk; }

  floatx4 acc[4][4];
#pragma unroll
  for (int i = 0; i < 4; ++i)
#pragma unroll
    for (int j = 0; j < 4; ++j) acc[i][j] = (floatx4){0.f, 0.f, 0.f, 0.f};

  const int lane = tid & 63, wave = tid >> 6;
  const int wm = (wave & 1) * 64, wn = (wave >> 1) * 64;
  const int fr = lane & 15, quad = lane >> 4;
  const int srow = tid >> 2;
  const int sc8 = (tid & 3) * 8;

  // LDS dest is wave-uniform base + lane*16B; layout is exactly lane-linear.
  unsigned short* lA0 = &As[wave * 512];
  unsigned short* lA1 = &As[2048 + wave * 512];
  unsigned short* lB0 = &Bs[wave * 512];
  unsigned short* lB1 = &Bs[2048 + wave * 512];

  for (int k0 = kbeg; k0 < kend; k0 += 32) {
    const long ra = (long)(bm + srow) * K + (k0 + sc8);
    const long rb = (long)(bn + srow) * K + (k0 + sc8);
    gload16(A + ra, lA0);
    gload16(A + ra + 64L * K, lA1);
    gload16(Bp + rb, lB0);
    gload16(Bp + rb + 64L * K, lB1);
    __syncthreads();
    bf16x8 af[4], bfr[4];
#pragma unroll
    for (int i = 0; i < 4; ++i) af[i] = *(const bf16x8*)(&As[(wm + i * 16 + fr) * 32 + quad * 8]);
#pragma unroll
    for (int j = 0; j < 4; ++j) bfr[j] = *(const bf16x8*)(&Bs[(wn + j * 16 + fr) * 32 + quad * 8]);
#pragma unroll
    for (int i = 0; i < 4; ++i)
#pragma unroll
      for (int j = 0; j < 4; ++j)
        acc[i][j] = __builtin_amdgcn_mfma_f32_16x16x32_bf16(af[i], bfr[j], acc[i][j], 0, 0, 0);
    __syncthreads();
  }

  if constexpr (EPI == EPI_LSE) {
    // store logits + per-row (max, sumexp) partial; two-pass, no dependent exp chains
    float2* sm = (float2*)As;
#pragma unroll
    for (int i = 0; i < 4; ++i) {
#pragma unroll
      for (int r = 0; r < 4; ++r) {
        const int m = bm + wm + i * 16 + quad * 4 + r;
        float mx = -INFINITY;
#pragma unroll
        for (int j = 0; j < 4; ++j) {
          const int n = bn + wn + j * 16 + fr;
          if (n < N) {
            const float val = acc[i][j][r];
            __builtin_nontemporal_store(val, &ga.outF[(long)m * ga.ldc + n]);
            mx = fmaxf(mx, val);
          }
        }
#pragma unroll
        for (int off = 1; off < 16; off <<= 1) mx = fmaxf(mx, __shfl_xor(mx, off));
        float ss = 0.f;
#pragma unroll
        for (int j = 0; j < 4; ++j) {
          const int n = bn + wn + j * 16 + fr;
          if (n < N) ss += __expf(acc[i][j][r] - mx);
        }
#pragma unroll
        for (int off = 1; off < 16; off <<= 1) ss += __shfl_xor(ss, off);
        if (fr == 0) {
          const int rl = wm + i * 16 + quad * 4 + r;
          sm[rl * 2 + (wave >> 1)] = make_float2(mx, ss);
        }
      }
    }
    __syncthreads();
    if (tid < 128) {
      const float2 a = sm[tid * 2], b = sm[tid * 2 + 1];
      const float M = fmaxf(a.x, b.x);
      const float S = a.y * __expf(a.x - M) + b.y * __expf(b.x - M);
      ga.lsePart[(long)(bm + tid) * ga.pn + blockIdx.x] = make_float2(M, S);
    }
  } else {
#pragma unroll
    for (int i = 0; i < 4; ++i) {
#pragma unroll
      for (int j = 0; j < 4; ++j) {
        const int n = bn + wn + j * 16 + fr;
#pragma unroll
        for (int r = 0; r < 4; ++r) {
          const int m = bm + wm + i * 16 + quad * 4 + r;
          const float val = acc[i][j][r];
          if constexpr (EPI == EPI_F32) {
            if (n < N) ga.outF[(long)z * ga.cBatch + (long)m * ga.ldc + n] = val;
          }
          if constexpr (EPI == EPI_SBF) {
            ga.outB[(long)z * TT * TT + (long)m * TT + n] = f2bf(val);
          }
          if constexpr (EPI == EPI_QKV) {
            const int b = m >> 10, t = m & 1023;
            const int sec = n >> 10, col = n & 1023;
            const int hd = col >> 6, dh = col & 63;
            const unsigned short bv = f2bf(val);
            if (sec == 0)      ga.q [((long)(b * HH + hd) * TT + t) * DHH + dh] = bv;
            else if (sec == 1) ga.kk[((long)(b * HH + hd) * TT + t) * DHH + dh] = bv;
            else               ga.vt[((long)(b * HH + hd) * DHH + dh) * TT + t] = bv;
          }
          if constexpr (EPI == EPI_GELU) {
            const float xx = val + ga.bias[n];
            const float gl = 0.5f * xx * (1.f + erff(xx * 0.7071067811865475f));
            ga.outB[(long)m * DFF + n] = f2bf(gl);
          }
        }
      }
    }
  }
}

// ---------- AV GEMM: att = w[T,T] x vt[64,T]^T, 128x64 tiles (no wasted MFMA) ----------
__global__ __launch_bounds__(256) void gemm_av_kernel(
    const unsigned short* __restrict__ W, const unsigned short* __restrict__ Vt,
    unsigned short* __restrict__ outB) {
  __shared__ __align__(16) unsigned short As[128 * 32];  // 8 KB
  __shared__ __align__(16) unsigned short Bs[64 * 32];   // 4 KB
  const int tid = threadIdx.x;
  const int bm = blockIdx.y * 128;
  const int z = blockIdx.z;
  const unsigned short* A = W + (long)z * TT * TT;
  const unsigned short* Bp = Vt + (long)z * DHH * TT;
  const int lane = tid & 63, wave = tid >> 6;
  const int fr = lane & 15, quad = lane >> 4;
  const int wm = wave * 32;
  const int srow = tid >> 2;
  const int sc8 = (tid & 3) * 8;

  floatx4 acc[2][4];
#pragma unroll
  for (int i = 0; i < 2; ++i)
#pragma unroll
    for (int j = 0; j < 4; ++j) acc[i][j] = (floatx4){0.f, 0.f, 0.f, 0.f};

  unsigned short* lA0 = &As[wave * 512];
  unsigned short* lA1 = &As[2048 + wave * 512];
  unsigned short* lB0 = &Bs[wave * 512];

  const int kend = bm + 128;  // w[m,k]==0 for k>m (exact zeros from softmax)
  for (int k0 = 0; k0 < kend; k0 += 32) {
    const long ra = (long)(bm + srow) * TT + (k0 + sc8);
    gload16(A + ra, lA0);
    gload16(A + ra + 64L * TT, lA1);
    gload16(Bp + (long)srow * TT + (k0 + sc8), lB0);
    __syncthreads();
    bf16x8 af[2], bfr[4];
#pragma unroll
    for (int i = 0; i < 2; ++i) af[i] = *(const bf16x8*)(&As[(wm + i * 16 + fr) * 32 + quad * 8]);
#pragma unroll
    for (int j = 0; j < 4; ++j) bfr[j] = *(const bf16x8*)(&Bs[(j * 16 + fr) * 32 + quad * 8]);
#pragma unroll
    for (int i = 0; i < 2; ++i)
#pragma unroll
      for (int j = 0; j < 4; ++j)
        acc[i][j] = __builtin_amdgcn_mfma_f32_16x16x32_bf16(af[i], bfr[j], acc[i][j], 0, 0, 0);
    __syncthreads();
  }

  const int b = z >> 4, hd = z & 15;
#pragma unroll
  for (int i = 0; i < 2; ++i) {
#pragma unroll
    for (int j = 0; j < 4; ++j) {
      const int n = j * 16 + fr;
#pragma unroll
      for (int r = 0; r < 4; ++r) {
        const int m = bm + wm + i * 16 + quad * 4 + r;
        outB[((long)(b * TT + m)) * DD + hd * DHH + n] = f2bf(acc[i][j][r]);
      }
    }
  }
}

// -------- transpose fp32 [R,C] -> bf16 [C,R], layer-batched via blockIdx.z --------
__global__ __launch_bounds__(256) void transpose_bf16_kernel(const float* __restrict__ src0,
    unsigned short* __restrict__ dst0, int R, int C, long sStride, long dStride) {
  const float* src = src0 + (long)blockIdx.z * sStride;
  unsigned short* dst = dst0 + (long)blockIdx.z * dStride;
  __shared__ float tile[32][33];
  const int c0 = blockIdx.x * 32, r0 = blockIdx.y * 32;
  const int tx = threadIdx.x & 31, ty = threadIdx.x >> 5;
#pragma unroll
  for (int rr = ty; rr < 32; rr += 8)
    tile[rr][tx] = src[(long)(r0 + rr) * C + (c0 + tx)];
  __syncthreads();
#pragma unroll
  for (int rr = ty; rr < 32; rr += 8)
    dst[(long)(c0 + rr) * R + (r0 + tx)] = f2bf(tile[tx][rr]);
}

__global__ __launch_bounds__(256) void convert_bf16_kernel(const float* __restrict__ in,
    unsigned short* __restrict__ out) {
  const long i = (long)blockIdx.x * 256 + threadIdx.x;
  const float4 v = ((const float4*)in)[i];
  ushort4 o;
  o.x = f2bf(v.x); o.y = f2bf(v.y); o.z = f2bf(v.z); o.w = f2bf(v.w);
  ((ushort4*)out)[i] = o;
}

__global__ __launch_bounds__(256) void embed_kernel(const int* __restrict__ idx,
    const float* __restrict__ emb, const float* __restrict__ pos, float* __restrict__ x) {
  const int bt = blockIdx.x;
  const int t = bt & (TT - 1);
  const int tok = idx[bt];
  const float4 e = ((const float4*)(emb + (long)tok * DD))[threadIdx.x];
  const float4 p = ((const float4*)(pos + (long)t * DD))[threadIdx.x];
  float4 o; o.x = e.x + p.x; o.y = e.y + p.y; o.z = e.z + p.z; o.w = e.w + p.w;
  ((float4*)(x + (long)bt * DD))[threadIdx.x] = o;
}

__global__ __launch_bounds__(256) void ln_kernel(const float* __restrict__ x,
    const float* __restrict__ g, const float* __restrict__ b, unsigned short* __restrict__ out) {
  const int row = blockIdx.x;
  const float4 v = ((const float4*)(x + (long)row * DD))[threadIdx.x];
  float s = v.x + v.y + v.z + v.w;
  float s2 = v.x * v.x + v.y * v.y + v.z * v.z + v.w * v.w;
  s = wave_sum(s); s2 = wave_sum(s2);
  __shared__ float ps[4], ps2[4];
  const int wv = threadIdx.x >> 6, lane = threadIdx.x & 63;
  if (lane == 0) { ps[wv] = s; ps2[wv] = s2; }
  __syncthreads();
  s = ps[0] + ps[1] + ps[2] + ps[3];
  s2 = ps2[0] + ps2[1] + ps2[2] + ps2[3];
  const float mean = s * (1.f / DD);
  const float var = s2 * (1.f / DD) - mean * mean;
  const float rs = rsqrtf(var + 1e-5f);
  const float4 gv = ((const float4*)g)[threadIdx.x];
  const float4 bv = ((const float4*)b)[threadIdx.x];
  ushort4 o;
  o.x = f2bf((v.x - mean) * rs * gv.x + bv.x);
  o.y = f2bf((v.y - mean) * rs * gv.y + bv.y);
  o.z = f2bf((v.z - mean) * rs * gv.z + bv.z);
  o.w = f2bf((v.w - mean) * rs * gv.w + bv.w);
  ((ushort4*)(out + (long)row * DD))[threadIdx.x] = o;
}

__global__ __launch_bounds__(256) void ln_fuse_kernel(float* __restrict__ x,
    const float* __restrict__ p0, const float* __restrict__ p1,
    const float* __restrict__ bias,
    const float* __restrict__ g, const float* __restrict__ b,
    unsigned short* __restrict__ out, int writeX) {
  const int row = blockIdx.x;
  float4 v = ((const float4*)(x + (long)row * DD))[threadIdx.x];
  const float4 a0 = ((const float4*)(p0 + (long)row * DD))[threadIdx.x];
  const float4 a1 = ((const float4*)(p1 + (long)row * DD))[threadIdx.x];
  v.x += a0.x + a1.x; v.y += a0.y + a1.y; v.z += a0.z + a1.z; v.w += a0.w + a1.w;
  if (bias) {
    const float4 bb = ((const float4*)bias)[threadIdx.x];
    v.x += bb.x; v.y += bb.y; v.z += bb.z; v.w += bb.w;
  }
  if (writeX) ((float4*)(x + (long)row * DD))[threadIdx.x] = v;
  float s = v.x + v.y + v.z + v.w;
  float s2 = v.x * v.x + v.y * v.y + v.z * v.z + v.w * v.w;
  s = wave_sum(s); s2 = wave_sum(s2);
  __shared__ float ps[4], ps2[4];
  const int wv = threadIdx.x >> 6, lane = threadIdx.x & 63;
  if (lane == 0) { ps[wv] = s; ps2[wv] = s2; }
  __syncthreads();
  s = ps[0] + ps[1] + ps[2] + ps[3];
  s2 = ps2[0] + ps2[1] + ps2[2] + ps2[3];
  const float mean = s * (1.f / DD);
  const float var = s2 * (1.f / DD) - mean * mean;
  const float rs = rsqrtf(var + 1e-5f);
  const float4 gv = ((const float4*)g)[threadIdx.x];
  const float4 bv = ((const float4*)b)[threadIdx.x];
  ushort4 o;
  o.x = f2bf((v.x - mean) * rs * gv.x + bv.x);
  o.y = f2bf((v.y - mean) * rs * gv.y + bv.y);
  o.z = f2bf((v.z - mean) * rs * gv.z + bv.z);
  o.w = f2bf((v.w - mean) * rs * gv.w + bv.w);
  ((ushort4*)(out + (long)row * DD))[threadIdx.x] = o;
}

// all layers batched via blockIdx.z
__global__ __launch_bounds__(256) void dists_kernel(const float* __restrict__ pos0,
    float* __restrict__ dout0, float* __restrict__ tre_acc) {
  const float* pos = pos0 + (long)blockIdx.z * TT * 3;
  float* dout = dout0 + (long)blockIdx.z * TT * TT;
  const int i = blockIdx.x;
  const float px = pos[i * 3], py = pos[i * 3 + 1], pz = pos[i * 3 + 2];
  float rsum = 0.f;
#pragma unroll
  for (int c = 0; c < 4; ++c) {
    const int j = c * 256 + threadIdx.x;
    const float dx = px - pos[j * 3];
    const float dy = py - pos[j * 3 + 1];
    const float dz = pz - pos[j * 3 + 2];
    const float sq = dx * dx + dy * dy + dz * dz;
    const float d = sq > 0.f ? sqrtf(sq) : 0.f;
    dout[(long)i * TT + j] = d;
    if (j != i) rsum += 1.f / (d + 1e-4f);
  }
  rsum = wave_sum(rsum);
  __shared__ float ps[4];
  const int wv = threadIdx.x >> 6, lane = threadIdx.x & 63;
  if (lane == 0) ps[wv] = rsum;
  __syncthreads();
  if (threadIdx.x == 0) atomicAdd(tre_acc, ps[0] + ps[1] + ps[2] + ps[3]);
}

// Causal-truncated softmax: skips loads for fully-masked chunks (j0 > i),
// skips all_w stores beyond i (output buffer is pre-zeroed; true values are
// exactly 0), and skips wb stores beyond the row's 128-block boundary
// (AV's K-clamp never reads there; garbage is masked next layer).
__global__ __launch_bounds__(256) void softmax_kernel(unsigned short* __restrict__ wb,
    const float* __restrict__ dists, float* __restrict__ W,
    float2* __restrict__ partials) {
  const long row = blockIdx.x;
  const int i = (int)(row & (TT - 1));
  unsigned short* sr = wb + row * TT;
  const float* dr = dists + (long)i * TT;
  const int j0 = threadIdx.x * 4;

  float d[4] = {0.f, 0.f, 0.f, 0.f};
  float sa[4] = {0.f, 0.f, 0.f, 0.f};
  const bool active = (j0 <= i);
  if (active) {
    const float4 dv = ((const float4*)dr)[threadIdx.x];
    const ushort4 su = ((const ushort4*)sr)[threadIdx.x];
    d[0] = dv.x; d[1] = dv.y; d[2] = dv.z; d[3] = dv.w;
    sa[0] = bf2f(su.x); sa[1] = bf2f(su.y); sa[2] = bf2f(su.z); sa[3] = bf2f(su.w);
  }
  float l[4];
  float mx = -INFINITY;
#pragma unroll
  for (int c = 0; c < 4; ++c) {
    float v = sa[c] * 0.125f - d[c];   // scale = 1/sqrt(64), PEN = 1.0
    if (j0 + c > i) v = -INFINITY;
    l[c] = v;
    mx = fmaxf(mx, v);
  }
  mx = wave_max(mx);
  __shared__ float rmax[4], rsm[4], rwd[4], rent[4];
  const int wv = threadIdx.x >> 6, lane = threadIdx.x & 63;
  if (lane == 0) rmax[wv] = mx;
  __syncthreads();
  mx = fmaxf(fmaxf(rmax[0], rmax[1]), fmaxf(rmax[2], rmax[3]));
  float e[4], sum = 0.f;
#pragma unroll
  for (int c = 0; c < 4; ++c) { e[c] = __expf(l[c] - mx); sum += e[c]; }
  sum = wave_sum(sum);
  if (lane == 0) rsm[wv] = sum;
  __syncthreads();
  sum = rsm[0] + rsm[1] + rsm[2] + rsm[3];
  const float inv = 1.f / sum;
  floatx4 wo;
  ushort4 bo;
  const float w0 = e[0] * inv, w1 = e[1] * inv, w2 = e[2] * inv, w3 = e[3] * inv;
  wo[0] = w0; wo[1] = w1; wo[2] = w2; wo[3] = w3;
  bo.x = f2bf(w0); bo.y = f2bf(w1); bo.z = f2bf(w2); bo.w = f2bf(w3);
  float wd = w0 * d[0] + w1 * d[1] + w2 * d[2] + w3 * d[3];
  float ent = -(w0 * __logf(w0 + 1e-9f) + w1 * __logf(w1 + 1e-9f)
        + w2 * __logf(w2 + 1e-9f) + w3 * __logf(w3 + 1e-9f));
  if (active)
    __builtin_nontemporal_store(wo, (floatx4*)(W + row * TT) + threadIdx.x);
  if (j0 <= (i | 127))
    ((ushort4*)sr)[threadIdx.x] = bo;
  wd = wave_sum(wd); ent = wave_sum(ent);
  if (lane == 0) { rwd[wv] = wd; rent[wv] = ent; }
  __syncthreads();
  if (threadIdx.x == 0) {
    partials[row] = make_float2(rwd[0] + rwd[1] + rwd[2] + rwd[3],
                                rent[0] + rent[1] + rent[2] + rent[3]);
  }
}

__global__ __launch_bounds__(256) void reduce_partials_kernel(const float2* __restrict__ p,
    int n, float* __restrict__ tde_acc, float* __restrict__ tfe_acc) {
  float wd = 0.f, ent = 0.f;
  for (int i = blockIdx.x * 256 + threadIdx.x; i < n; i += gridDim.x * 256) {
    const float2 v = p[i];
    wd += v.x; ent += v.y;
  }
  wd = wave_sum(wd); ent = wave_sum(ent);
  __shared__ float pw[4], pe[4];
  const int wv = threadIdx.x >> 6, lane = threadIdx.x & 63;
  if (lane == 0) { pw[wv] = wd; pe[wv] = ent; }
  __syncthreads();
  if (threadIdx.x == 0) {
    atomicAdd(tde_acc, pw[0] + pw[1] + pw[2] + pw[3]);
    atomicAdd(tfe_acc, pe[0] + pe[1] + pe[2] + pe[3]);
  }
}

__global__ __launch_bounds__(256) void ce_reduce_kernel(const float2* __restrict__ part,
    const float* __restrict__ logits, const int* __restrict__ targets,
    float* __restrict__ ce_acc, int pn) {
  const int row = blockIdx.x;
  const float2* pr = part + (long)row * pn;
  float m = -INFINITY, s = 0.f;
  for (int i = threadIdx.x; i < pn; i += 256) {
    const float2 v = pr[i];
    const float M = fmaxf(m, v.x);
    s = s * __expf(m - M) + v.y * __expf(v.x - M);
    m = M;
  }
#pragma unroll
  for (int off = 1; off < 64; off <<= 1) {
    const float mo = __shfl_xor(m, off), so = __shfl_xor(s, off);
    const float M = fmaxf(m, mo);
    s = s * __expf(m - M) + so * __expf(mo - M);
    m = M;
  }
  __shared__ float pm[4], psv[4];
  const int wv = threadIdx.x >> 6, lane = threadIdx.x & 63;
  if (lane == 0) { pm[wv] = m; psv[wv] = s; }
  __syncthreads();
  if (threadIdx.x == 0) {
    const float M = fmaxf(fmaxf(pm[0], pm[1]), fmaxf(pm[2], pm[3]));
    const float S = psv[0] * __expf(pm[0] - M) + psv[1] * __expf(pm[1] - M)
                  + psv[2] * __expf(pm[2] - M) + psv[3] * __expf(pm[3] - M);
    atomicAdd(ce_acc, M + logf(S) - logits[(long)row * VV + targets[row]]);
  }
}

__global__ void zero_acc_kernel(float* p) { if (threadIdx.x < 4) p[threadIdx.x] = 0.f; }

__global__ void finalize_kernel(const float* __restrict__ acc, float* __restrict__ o) {
  if (threadIdx.x == 0) {
    const float tde = acc[0] * (1.f / 32768.f);
    const float tfe = acc[1] * (1.f / 32768.f);
    const float tre = acc[2] * (1.f / 1047552.f);
    const float ce = acc[3] * (1.f / 2048.f);
    o[0] = ce + 0.01f * tde + 0.1f * tfe + 0.01f * tre;
    o[1] = tde; o[2] = tfe; o[3] = tre;
  }
}

extern "C" void kernel_launch(void* const* d_in, const int* in_sizes, int n_in,
                              void* d_out, int out_size, void* d_ws, size_t ws_size,
                              hipStream_t stream) {
  const int* idx = (const int*)d_in[0];
  const int* targets = (const int*)d_in[1];
  const float* emb = (const float*)d_in[2];
  const float* pos_emb = (const float*)d_in[3];
  const float* positions = (const float*)d_in[4];
  const float* ln1_g = (const float*)d_in[5];
  const float* ln1_b = (const float*)d_in[6];
  const float* ln2_g = (const float*)d_in[7];
  const float* ln2_b = (const float*)d_in[8];
  const float* lnf_g = (const float*)d_in[9];
  const float* lnf_b = (const float*)d_in[10];
  const float* qkv_w = (const float*)d_in[11];
  const float* proj_w = (const float*)d_in[12];
  const float* w1 = (const float*)d_in[13];
  const float* b1 = (const float*)d_in[14];
  const float* w2 = (const float*)d_in[15];
  const float* b2 = (const float*)d_in[16];

  float* out = (float*)d_out;
  char* ws = (char*)d_ws;

  const long LOGITS_N = (long)BB * TT * VV;
  const long SCAL_OFF = LOGITS_N;
  const long ALLW_OFF = LOGITS_N + 4;
  const long ALLW_STRIDE = (long)BB * HH * TT * TT;
  const long ALLD_OFF = ALLW_OFF + 4 * ALLW_STRIDE;

  unsigned short* wt_qkv  = (unsigned short*)(ws);
  unsigned short* wt_proj = (unsigned short*)(ws + 25165824L);
  unsigned short* wt_w1   = (unsigned short*)(ws + 33554432L);
  unsigned short* wt_w2   = (unsigned short*)(ws + 67108864L);
  unsigned short* emb_bf  = (unsigned short*)(ws + 100663296L);
  float*          x       = (float*)(ws + 203589632L);
  unsigned short* h_bf    = (unsigned short*)(ws + 211978240L);
  unsigned short* q_bf    = (unsigned short*)(ws + 216172544L);
  unsigned short* k_bf    = (unsigned short*)(ws + 220366848L);
  unsigned short* vt_bf   = (unsigned short*)(ws + 224561152L);
  unsigned short* attb_bf = (unsigned short*)(ws + 228755456L);
  unsigned short* g_bf    = (unsigned short*)(ws + 232949760L);
  unsigned short* w_bf    = (unsigned short*)(ws + 249726976L);
  float*          accs    = (float*)(ws + 316835840L);

  // scratch overlays (lifetime-checked; see R3 notes)
  float2* smpart = (float2*)attb_bf;
  float2* lsepart = (float2*)wt_qkv;
  float* pp = (float*)w_bf;
  float* fp = (float*)w_bf + 2L * 2048 * DD;
  const long RES_PART = (long)2048 * DD;
  const int LSE_PN = (VV + 127) / 128;   // 393

  const dim3 blk(256);

  transpose_bf16_kernel<<<dim3(3 * DD / 32, DD / 32, LL), blk, 0, stream>>>(
      qkv_w, wt_qkv, DD, 3 * DD, (long)DD * 3 * DD, (long)DD * 3 * DD);
  transpose_bf16_kernel<<<dim3(DD / 32, DD / 32, LL), blk, 0, stream>>>(
      proj_w, wt_proj, DD, DD, (long)DD * DD, (long)DD * DD);
  transpose_bf16_kernel<<<dim3(DFF / 32, DD / 32, LL), blk, 0, stream>>>(
      w1, wt_w1, DD, DFF, (long)DD * DFF, (long)DD * DFF);
  transpose_bf16_kernel<<<dim3(DD / 32, DFF / 32, LL), blk, 0, stream>>>(
      w2, wt_w2, DFF, DD, (long)DFF * DD, (long)DFF * DD);
  convert_bf16_kernel<<<VV, blk, 0, stream>>>(emb, emb_bf);

  embed_kernel<<<BB * TT, blk, 0, stream>>>(idx, emb, pos_emb, x);
  zero_acc_kernel<<<1, 64, 0, stream>>>(accs);

  dists_kernel<<<dim3(TT, 1, LL), blk, 0, stream>>>(positions, out + ALLD_OFF, accs + 2);

  for (int l = 0; l < LL; ++l) {
    float* allw_l = out + ALLW_OFF + (long)l * ALLW_STRIDE;
    float* alld_l = out + ALLD_OFF + (long)l * (long)TT * TT;

    if (l == 0)
      ln_kernel<<<BB * TT, blk, 0, stream>>>(x, ln1_g, ln1_b, h_bf);
    else
      ln_fuse_kernel<<<BB * TT, blk, 0, stream>>>(x, fp, fp + RES_PART,
          b2 + (long)(l - 1) * DD, ln1_g + l * DD, ln1_b + l * DD, h_bf, 1);

    { GemmArgs ga = {}; ga.A = h_bf; ga.B = wt_qkv + (long)l * 3 * DD * DD;
      ga.M = BB * TT; ga.N = 3 * DD; ga.K = DD;
      ga.q = q_bf; ga.kk = k_bf; ga.vt = vt_bf;
      gemm_kernel<EPI_QKV><<<dim3(24, 16, 1), blk, 0, stream>>>(ga); }

    { GemmArgs ga = {}; ga.A = q_bf; ga.B = k_bf;
      ga.aBatch = (long)TT * DHH; ga.bBatch = (long)TT * DHH;
      ga.M = TT; ga.N = TT; ga.K = DHH;
      ga.outB = w_bf;
      gemm_kernel<EPI_SBF><<<dim3(36, 1, BB * HH), blk, 0, stream>>>(ga); }

    softmax_kernel<<<BB * HH * TT, blk, 0, stream>>>(w_bf, alld_l, allw_l, smpart);
    reduce_partials_kernel<<<64, blk, 0, stream>>>(smpart, BB * HH * TT, accs + 0, accs + 1);

    gemm_av_kernel<<<dim3(1, 8, BB * HH), blk, 0, stream>>>(w_bf, vt_bf, attb_bf);

    { GemmArgs ga = {}; ga.A = attb_bf; ga.B = wt_proj + (long)l * DD * DD;
      ga.M = BB * TT; ga.N = DD; ga.K = DD; ga.ldc = DD;
      ga.outF = pp; ga.cBatch = RES_PART; ga.kchunk = DD / 2;
      gemm_kernel<EPI_F32><<<dim3(8, 16, 2), blk, 0, stream>>>(ga); }

    ln_fuse_kernel<<<BB * TT, blk, 0, stream>>>(x, pp, pp + RES_PART,
        nullptr, ln2_g + l * DD, ln2_b + l * DD, h_bf, 1);

    { GemmArgs ga = {}; ga.A = h_bf; ga.B = wt_w1 + (long)l * DFF * DD;
      ga.M = BB * TT; ga.N = DFF; ga.K = DD;
      ga.bias = b1 + (long)l * DFF; ga.outB = g_bf;
      gemm_kernel<EPI_GELU><<<dim3(32, 16, 1), blk, 0, stream>>>(ga); }

    { GemmArgs ga = {}; ga.A = g_bf; ga.B = wt_w2 + (long)l * DD * DFF;
      ga.M = BB * TT; ga.N = DD; ga.K = DFF; ga.ldc = DD;
      ga.outF = fp; ga.cBatch = RES_PART; ga.kchunk = DFF / 2;
      gemm_kernel<EPI_F32><<<dim3(8, 16, 2), blk, 0, stream>>>(ga); }
  }

  // final LN: x is dead afterwards -> skip writeback
  ln_fuse_kernel<<<BB * TT, blk, 0, stream>>>(x, fp, fp + RES_PART,
      b2 + (long)(LL - 1) * DD, lnf_g, lnf_b, h_bf, 0);

  { GemmArgs ga = {}; ga.A = h_bf; ga.B = emb_bf;
    ga.M = BB * TT; ga.N = VV; ga.K = DD;
    ga.outF = out; ga.ldc = VV; ga.cBatch = 0;
    ga.lsePart = lsepart; ga.pn = LSE_PN;
    gemm_kernel<EPI_LSE><<<dim3(LSE_PN, 16, 1), blk, 0, stream>>>(ga); }

  ce_reduce_kernel<<<BB * TT, blk, 0, stream>>>(lsepart, out, targets, accs + 3, LSE_PN);
  finalize_kernel<<<1, 64, 0, stream>>>(accs, out + SCAL_OFF);
}